// Round 8
// baseline (364.332 us; speedup 1.0000x reference)
//
#include <hip/hip_runtime.h>
#include <hip/hip_bf16.h>
#include <stdint.h>

#define BLOCK 256
#define SBLOCK 128
#define MAXO 64
#define TK_THREADS 1024
#define CK_MAX 4096
#define NBIN 4096

// ---------------- K1: per-object argmax over P (block per (n,o)) + init ----------------
__global__ void match_object_kernel(const float* __restrict__ boxes,
                                    const float* __restrict__ priors,
                                    int* __restrict__ pfop,
                                    float* __restrict__ acc, int* __restrict__ n_pos,
                                    unsigned* __restrict__ done,
                                    int* __restrict__ hzero,   // hcnt..hsum contiguous dwords
                                    long long hlen,
                                    int N, int P, int O) {
    __shared__ unsigned long long swm[4];
    int idx = blockIdx.x, tid = threadIdx.x;
    if (idx == 0) {                       // init for later dispatches (stream-ordered)
        for (int j = tid; j < N; j += BLOCK) n_pos[j] = 0;
        if (tid >= 64 && tid < 67) acc[tid - 64] = 0.f;
        if (tid == 96) *done = 0u;
    }
    // zero the per-image histograms (grid-stride over all blocks)
    for (long long j = (long long)idx * BLOCK + tid; j < hlen;
         j += (long long)gridDim.x * BLOCK)
        hzero[j] = 0;

    const float* b = boxes + (size_t)idx * 4;
    float bx0 = b[0], by0 = b[1], bx1 = b[2], by1 = b[3];
    float areaa = (bx1 - bx0) * (by1 - by0);

    unsigned long long best = 0ULL;
    for (int p = tid; p < P; p += BLOCK) {
        float4 pr = ((const float4*)priors)[p];
        float px0 = pr.x - pr.z * 0.5f, py0 = pr.y - pr.w * 0.5f;
        float px1 = pr.x + pr.z * 0.5f, py1 = pr.y + pr.w * 0.5f;
        float areab = (px1 - px0) * (py1 - py0);
        float ltx = fmaxf(bx0, px0), lty = fmaxf(by0, py0);
        float rbx = fminf(bx1, px1), rby = fminf(by1, py1);
        float wx = fmaxf(rbx - ltx, 0.f), wy = fmaxf(rby - lty, 0.f);
        float inter = wx * wy;
        float iou = inter / (areaa + areab - inter);
        unsigned long long cand = (((unsigned long long)__float_as_uint(iou)) << 32) |
                                  (unsigned long long)(0xFFFFFFFFu - (unsigned)p);
        if (cand > best) best = cand;     // larger iou; tie -> smaller p (numpy first)
    }
    #pragma unroll
    for (int off = 32; off >= 1; off >>= 1) {
        unsigned long long other = __shfl_down(best, off);
        if (other > best) best = other;
    }
    if ((tid & 63) == 0) swm[tid >> 6] = best;
    __syncthreads();
    if (tid == 0) {
        unsigned long long r = swm[0];
        for (int w = 1; w < BLOCK / 64; ++w) if (swm[w] > r) r = swm[w];
        pfop[idx] = (int)(0xFFFFFFFFu - (unsigned)(r & 0xFFFFFFFFull));
    }
}

// ---------------- K2+K3 fused v8: LDS-bounce staging + global histogram build ----------------
// v7 structure (LDS-bounce, thread-per-row, 47us) + 2 fire-and-forget global atomics
// per row into per-image histograms (counts + f32 sums, 4096 bins by top-12 float
// bits). These feed topk v2, which then needs only ONE O(P) pass instead of three.
__global__ void __launch_bounds__(SBLOCK)
fused_staged_kernel(const float* __restrict__ boxes,
                    const float* __restrict__ priors,
                    const float* __restrict__ locs,
                    const int* __restrict__ labels,
                    const int* __restrict__ pfop,
                    const float* __restrict__ scores,
                    float* __restrict__ ce_neg,
                    float* __restrict__ pb_loc, float* __restrict__ pb_pce,
                    int* __restrict__ pb_npos,
                    int* __restrict__ hcnt, float* __restrict__ hsum,
                    int N, int P, int O) {
    __shared__ float4 sstage4[SBLOCK * 81 / 4];   // 2592 float4 = 41,472 B
    __shared__ float sbx[MAXO * 4];
    __shared__ int   spf[MAXO];
    __shared__ int   slab[MAXO];
    __shared__ float sl[2], sp[2]; __shared__ int sn[2];
    const float* sstage = (const float*)sstage4;

    int n = blockIdx.y, bx = blockIdx.x, tid = threadIdx.x;
    int w = tid >> 6, lane = tid & 63;
    int p0 = bx * SBLOCK;
    int rows = P - p0; if (rows > SBLOCK) rows = SBLOCK;   // rows % 4 == 0 (P % 4 == 0)
    int p = p0 + tid;
    bool valid = tid < rows;
    size_t t = (size_t)n * P + p;

    // ---- metadata -> LDS (small), prior/loc -> regs ----
    for (int i = tid; i < O * 4; i += SBLOCK) sbx[i] = boxes[(size_t)n * O * 4 + i];
    for (int i = tid; i < O; i += SBLOCK) { spf[i] = pfop[n * O + i]; slab[i] = labels[n * O + i]; }
    float4 pr = make_float4(0.f, 0.f, 1.f, 1.f);
    float4 pl = make_float4(0.f, 0.f, 0.f, 0.f);
    if (valid) {
        pr = ((const float4*)priors)[p];
        pl = ((const float4*)locs)[t];
    }

    // ---- stage: coalesced float4 copy, identity layout (global chunk is contiguous) ----
    const float4* chunk = (const float4*)(scores + ((size_t)n * P + p0) * 81);
    if (rows == SBLOCK) {
        #pragma unroll
        for (int j = 0; j < 20; ++j)
            sstage4[j * SBLOCK + tid] = chunk[j * SBLOCK + tid];
        if (tid < 32)                                  // tail: 2560..2591
            sstage4[20 * SBLOCK + tid] = chunk[20 * SBLOCK + tid];
    } else {                                           // partial tile (one per image)
        int nf4 = rows * 81 / 4;
        for (int j = 0; j < 21; ++j) {
            int idx = j * SBLOCK + tid;
            if (idx < nf4) sstage4[idx] = chunk[idx];
        }
    }
    __syncthreads();

    // ---- consume: thread-per-row from LDS ----
    float my_loc = 0.f, my_pce = 0.f; int my_pos = 0;
    if (valid) {
        const float* row = sstage + tid * 81;          // bank stride 17: conflict-free
        float e = 0.f;
        #pragma unroll
        for (int j = 0; j < 81; ++j) e += __expf(row[j]);

        // match (v2 semantics): strict > = first index; forced match last-wins
        float px0 = pr.x - pr.z * 0.5f, py0 = pr.y - pr.w * 0.5f;
        float px1 = pr.x + pr.z * 0.5f, py1 = pr.y + pr.w * 0.5f;
        float areab = (px1 - px0) * (py1 - py0);
        float best = -1.f; int bo = 0;
        for (int o = 0; o < O; ++o) {                  // sbx reads wave-broadcast
            float x0 = sbx[o*4+0], y0 = sbx[o*4+1], x1 = sbx[o*4+2], y1 = sbx[o*4+3];
            float ltx = fmaxf(x0, px0), lty = fmaxf(y0, py0);
            float rbx = fminf(x1, px1), rby = fminf(y1, py1);
            float wx = fmaxf(rbx - ltx, 0.f), wy = fmaxf(rby - lty, 0.f);
            float inter = wx * wy;
            float areao = (x1 - x0) * (y1 - y0);
            float iou = inter / (areao + areab - inter);
            if (iou > best) { best = iou; bo = o; }
        }
        int fo = -1;
        for (int o = 0; o < O; ++o) if (spf[o] == p) fo = o;
        int obj; float ov;
        if (fo >= 0) { obj = fo; ov = 1.0f; }
        else         { obj = bo; ov = best; }
        int tc = (ov < 0.5f) ? 0 : slab[obj];

        float stc = row[tc];                           // free: already staged
        float ce = logf(e) - stc;
        bool pos = (tc != 0);
        float cv = pos ? 0.f : ce;
        ce_neg[t] = cv;                                // coalesced store
        unsigned key = __float_as_uint(cv);
        int bin = (int)(key >> 20);
        atomicAdd(&hcnt[n * NBIN + bin], 1);           // fire-and-forget, overlapped
        atomicAdd(&hsum[n * NBIN + bin], cv);
        if (pos) {
            my_pce = ce; my_pos = 1;
            float x0 = sbx[obj*4+0], y0 = sbx[obj*4+1], x1 = sbx[obj*4+2], y1 = sbx[obj*4+3];
            float cx = (x0 + x1) * 0.5f, cy = (y0 + y1) * 0.5f;
            float bw = x1 - x0, bh = y1 - y0;
            float g0 = (cx - pr.x) / (pr.z / 10.0f);
            float g1 = (cy - pr.y) / (pr.w / 10.0f);
            float g2 = logf(bw / pr.z) * 5.0f;
            float g3 = logf(bh / pr.w) * 5.0f;
            my_loc = fabsf(pl.x-g0) + fabsf(pl.y-g1) + fabsf(pl.z-g2) + fabsf(pl.w-g3);
        }
    }

    // ---- block partials: plain stores, no hot-path atomics ----
    #pragma unroll
    for (int off = 32; off >= 1; off >>= 1) {
        my_loc += __shfl_down(my_loc, off);
        my_pce += __shfl_down(my_pce, off);
        my_pos += __shfl_down(my_pos, off);
    }
    if (lane == 0) { sl[w] = my_loc; sp[w] = my_pce; sn[w] = my_pos; }
    __syncthreads();
    if (tid == 0) {
        int npb = gridDim.x;
        pb_loc[n * npb + bx]  = sl[0] + sl[1];
        pb_pce[n * npb + bx]  = sp[0] + sp[1];
        pb_npos[n * npb + bx] = sn[0] + sn[1];
    }
}

// ---------------- fallback K2: per-prior match -> tcarr (any C path) ----------------
__global__ void match_prior_kernel(const float* __restrict__ boxes,
                                   const float* __restrict__ priors,
                                   const float* __restrict__ locs,
                                   const int* __restrict__ labels,
                                   const int* __restrict__ pfop,
                                   int* __restrict__ tcarr,
                                   float* __restrict__ acc, int* __restrict__ n_pos,
                                   int N, int P, int O) {
    __shared__ float sbx[MAXO * 4];
    __shared__ float sarea[MAXO];
    __shared__ int   spf[MAXO];
    __shared__ int   slab[MAXO];
    int n = blockIdx.y, tid = threadIdx.x;
    if (tid < O * 4) sbx[tid] = boxes[(size_t)n * O * 4 + tid];
    if (tid >= 128 && tid < 128 + O) spf[tid - 128]  = pfop[n * O + (tid - 128)];
    if (tid >= 192 && tid < 192 + O) slab[tid - 192] = labels[n * O + (tid - 192)];
    __syncthreads();
    if (tid < O)
        sarea[tid] = (sbx[tid*4+2] - sbx[tid*4+0]) * (sbx[tid*4+3] - sbx[tid*4+1]);
    __syncthreads();

    int p = blockIdx.x * BLOCK + tid;
    bool valid = p < P;
    float my_loc = 0.f; int my_pos = 0;
    if (valid) {
        float4 pr = ((const float4*)priors)[p];
        float px0 = pr.x - pr.z * 0.5f, py0 = pr.y - pr.w * 0.5f;
        float px1 = pr.x + pr.z * 0.5f, py1 = pr.y + pr.w * 0.5f;
        float areab = (px1 - px0) * (py1 - py0);

        float best = -1.f; int bo = 0;
        for (int o = 0; o < O; ++o) {
            float ltx = fmaxf(sbx[o*4+0], px0);
            float lty = fmaxf(sbx[o*4+1], py0);
            float rbx = fminf(sbx[o*4+2], px1);
            float rby = fminf(sbx[o*4+3], py1);
            float wx = fmaxf(rbx - ltx, 0.f), wy = fmaxf(rby - lty, 0.f);
            float inter = wx * wy;
            float iou = inter / (sarea[o] + areab - inter);
            if (iou > best) { best = iou; bo = o; }
        }
        int fo = -1;
        for (int o = 0; o < O; ++o) if (spf[o] == p) fo = o;
        int obj; float ov;
        if (fo >= 0) { obj = fo; ov = 1.0f; }
        else         { obj = bo; ov = best; }
        int lab = slab[obj];
        int tc = (ov < 0.5f) ? 0 : lab;
        tcarr[(size_t)n * P + p] = tc;
        if (tc != 0) {
            my_pos = 1;
            float x0 = sbx[obj*4+0], y0 = sbx[obj*4+1], x1 = sbx[obj*4+2], y1 = sbx[obj*4+3];
            float cx = (x0 + x1) * 0.5f, cy = (y0 + y1) * 0.5f;
            float w = x1 - x0, h = y1 - y0;
            float g0 = (cx - pr.x) / (pr.z / 10.0f);
            float g1 = (cy - pr.y) / (pr.w / 10.0f);
            float g2 = logf(w / pr.z) * 5.0f;
            float g3 = logf(h / pr.w) * 5.0f;
            const float* pl = locs + ((size_t)n * P + p) * 4;
            my_loc = fabsf(pl[0]-g0) + fabsf(pl[1]-g1) + fabsf(pl[2]-g2) + fabsf(pl[3]-g3);
        }
    }
    #pragma unroll
    for (int off = 32; off >= 1; off >>= 1) {
        my_loc += __shfl_down(my_loc, off);
        my_pos += __shfl_down(my_pos, off);
    }
    if ((tid & 63) == 0 && my_pos) {
        atomicAdd(&acc[0], my_loc);
        atomicAdd(&n_pos[n], my_pos);
    }
}

// ---------------- generic fallback (any C) ----------------
__global__ void loss_generic_kernel(const float* __restrict__ scores,
                                    const int* __restrict__ tcarr,
                                    float* __restrict__ ce_neg, float* __restrict__ acc,
                                    int NP, int C) {
    int t = blockIdx.x * blockDim.x + threadIdx.x;
    if (t >= NP) return;
    int tc = tcarr[t];
    const float* s = scores + (size_t)t * C;
    float m = -3.0e38f;
    for (int j = 0; j < C; ++j) m = fmaxf(m, s[j]);
    float l = 0.f, stc = 0.f;
    for (int j = 0; j < C; ++j) {
        float v = s[j];
        l += __expf(v - m);
        if (j == tc) stc = v;
    }
    float ce = m + logf(l) - stc;
    bool pos = (tc != 0);
    ce_neg[t] = pos ? 0.f : ce;
    if (pos) atomicAdd(&acc[1], ce);
}

// ---------------- K4 v2: histogram-driven top-k + fused final combine ----------------
// New path (npb>0): counts+sums precomputed by fused. Phase B finds the threshold bin
// AND the above-bin sum via wave-shuffle suffix scans (2 barriers, no 20-round LDS
// scan, no staging pass, no histogram build). Phase C: ONE pass over the row with
// ballot-aggregated collection (1 atomic/wave). Phases D/E: 256-bin refine + rank on
// the small boundary set -- identical tie semantics to the old (passing) code.
__global__ void topk_final_kernel(const float* __restrict__ ce_neg,
                                  int* __restrict__ n_pos,
                                  const float* __restrict__ pb_loc,
                                  const float* __restrict__ pb_pce,
                                  const int* __restrict__ pb_npos, int npb,
                                  const int* __restrict__ hcnt,
                                  const float* __restrict__ hsum,
                                  float* __restrict__ acc, unsigned* __restrict__ done,
                                  int N, int P, unsigned* __restrict__ out) {
    __shared__ unsigned skeys[8732];  // old path only
    __shared__ int hist[4096];        // old: hist/ckeys; new: ckeys
    __shared__ int part[1024];        // old: scan; new: hist2 (first 256)
    __shared__ int wtot[16]; __shared__ float wtotf[16];
    __shared__ int s_tb, s_ca, s_tb2, s_ca2, s_cnt, s_np, s_htb;
    __shared__ float s_b0, s_ftb;
    __shared__ float shf[16];
    int n = blockIdx.x, tid = threadIdx.x;
    int w = tid >> 6, lane = tid & 63;

    int k;
    if (npb > 0) {                    // fused path: reduce per-block partials (wave 0)
        if (tid < 64) {
            float psl = 0.f, psp = 0.f; int psn = 0;
            for (int i = tid; i < npb; i += 64) {
                psl += pb_loc[n * npb + i];
                psp += pb_pce[n * npb + i];
                psn += pb_npos[n * npb + i];
            }
            #pragma unroll
            for (int off = 32; off >= 1; off >>= 1) {
                psl += __shfl_down(psl, off);
                psp += __shfl_down(psp, off);
                psn += __shfl_down(psn, off);
            }
            if (tid == 0) {
                s_np = psn;
                n_pos[n] = psn;                       // plain store; fenced before done++
                if (psl != 0.f) atomicAdd(&acc[0], psl);
                if (psp != 0.f) atomicAdd(&acc[1], psp);
            }
        }
        __syncthreads();
        k = 3 * s_np;
    } else {
        k = 3 * n_pos[n];
    }
    if (k > P) k = P;
    float bsum = 0.f;

    if (k > 0 && npb > 0) {
        // ---- Phase B: threshold bin via shuffle suffix-scan over 4096 bins ----
        int b0 = tid * 4;
        int4   hc = *(const int4*)&hcnt[(size_t)n * NBIN + b0];
        float4 hf = *(const float4*)&hsum[(size_t)n * NBIN + b0];
        int   lc = hc.x + hc.y + hc.z + hc.w;
        float lf = hf.x + hf.y + hf.z + hf.w;
        int si = lc; float sf = lf;
        #pragma unroll
        for (int off = 1; off < 64; off <<= 1) {       // wave inclusive suffix
            int ti = __shfl(si, lane + off);
            float tf = __shfl(sf, lane + off);
            if (lane + off < 64) { si += ti; sf += tf; }
        }
        if (lane == 0) { wtot[w] = si; wtotf[w] = sf; }
        __syncthreads();
        if (tid < 16) {                                // wave 0: suffix over 16 totals
            int ov = wtot[tid]; float ovf = wtotf[tid];
            int v = ov; float vf = ovf;
            #pragma unroll
            for (int off = 1; off < 16; off <<= 1) {
                int tv = __shfl(v, lane + off);
                float tvf = __shfl(vf, lane + off);
                if (lane + off < 16) { v += tv; vf += tvf; }
            }
            wtot[tid] = v - ov; wtotf[tid] = vf - ovf; // exclusive
        }
        if (tid == 0) s_cnt = 0;
        __syncthreads();
        int   after  = wtot[w] + (si - lc);            // counts in bins > this group
        float afterf = wtotf[w] + (sf - lf);
        int sf3 = after,       sf2 = sf3 + hc.w, sf1 = sf2 + hc.z, sf0 = sf1 + hc.y;
        float ff3 = afterf,    ff2 = ff3 + hf.w, ff1 = ff2 + hf.z, ff0 = ff1 + hf.y;
        if (sf0 < k && k <= sf0 + hc.x) { s_tb = b0;   s_ca = sf0; s_b0 = ff0; s_htb = hc.x; s_ftb = hf.x; }
        if (sf1 < k && k <= sf1 + hc.y) { s_tb = b0+1; s_ca = sf1; s_b0 = ff1; s_htb = hc.y; s_ftb = hf.y; }
        if (sf2 < k && k <= sf2 + hc.z) { s_tb = b0+2; s_ca = sf2; s_b0 = ff2; s_htb = hc.z; s_ftb = hf.z; }
        if (sf3 < k && k <= sf3 + hc.w) { s_tb = b0+3; s_ca = sf3; s_b0 = ff3; s_htb = hc.w; s_ftb = hf.w; }
        __syncthreads();
        int tb = s_tb, kk = k - s_ca;
        bool shortcut = (kk == s_htb);                 // whole bin included: no row pass
        float ssum = 0.f;

        if (!shortcut) {
            // ---- Phase C: one row pass, ballot-aggregated collect of bin-tb keys ----
            unsigned* ckeys = (unsigned*)hist;
            const float* row = ce_neg + (size_t)n * P;
            for (int i = tid; i < P; i += TK_THREADS) {
                unsigned key = __float_as_uint(row[i]);
                bool pred = (int)(key >> 20) == tb;
                unsigned long long bal = __ballot(pred);
                if (bal) {
                    int ldr = __builtin_ctzll(bal);
                    int base = 0;
                    if (lane == ldr) base = atomicAdd(&s_cnt, __builtin_popcountll(bal));
                    base = __shfl(base, ldr);
                    if (pred) {
                        int slot = base + __builtin_popcountll(bal & ((1ull << lane) - 1ull));
                        if (slot < CK_MAX) ckeys[slot] = key;
                    }
                }
            }
            __syncthreads();
            int m = s_cnt; if (m > CK_MAX) m = CK_MAX;

            // ---- Phase D: 256-bin refine within bin tb ----
            if (tid < 256) part[tid] = 0;
            __syncthreads();
            for (int i = tid; i < m; i += TK_THREADS)
                atomicAdd(&part[(ckeys[i] >> 12) & 255u], 1);
            __syncthreads();
            if (tid < 256) {
                int cum = 0;
                for (int b2 = tid + 1; b2 < 256; ++b2) cum += part[b2];
                int h = part[tid];
                if (cum < kk && kk <= cum + h) { s_tb2 = tid; s_ca2 = cum; }
            }
            __syncthreads();
            int tb2 = s_tb2, kk2 = kk - s_ca2;

            // ---- Phase E: sum above sub-bin; rank within boundary sub-bin ----
            for (int i = tid; i < m; i += TK_THREADS) {
                unsigned key = ckeys[i];
                int b2 = (key >> 12) & 255u;
                if (b2 > tb2) ssum += __uint_as_float(key);
                else if (b2 == tb2) {
                    int rank = 0;
                    for (int j = 0; j < m; ++j) {
                        unsigned kj = ckeys[j];
                        if (((kj >> 12) & 255u) == (unsigned)tb2)
                            rank += (kj > key) || (kj == key && j < i);
                    }
                    if (rank < kk2) ssum += __uint_as_float(key);
                }
            }
        }
        #pragma unroll
        for (int off = 32; off >= 1; off >>= 1) ssum += __shfl_down(ssum, off);
        __syncthreads();
        if ((tid & 63) == 0) shf[tid >> 6] = ssum;
        __syncthreads();
        if (tid == 0) {
            float tot = 0.f;
            for (int i = 0; i < 16; ++i) tot += shf[i];
            bsum = tot + s_b0 + (shortcut ? s_ftb : 0.f);
        }
    } else if (k > 0) {
        // ---- old 3-pass radix path (generic fallback; unchanged semantics) ----
        const float* row = ce_neg + (size_t)n * P;
        for (int i = tid; i < P; i += TK_THREADS) skeys[i] = __float_as_uint(row[i]);
        #pragma unroll
        for (int b = 0; b < 4; ++b) hist[tid * 4 + b] = 0;
        __syncthreads();
        for (int i = tid; i < P; i += TK_THREADS) atomicAdd(&hist[skeys[i] >> 20], 1);
        __syncthreads();
        int h0 = hist[tid*4], h1 = hist[tid*4+1], h2 = hist[tid*4+2], h3 = hist[tid*4+3];
        part[tid] = h0 + h1 + h2 + h3;
        __syncthreads();
        for (int s = 1; s < 1024; s <<= 1) {
            int v = part[tid] + ((tid + s < 1024) ? part[tid + s] : 0);
            __syncthreads();
            part[tid] = v;
            __syncthreads();
        }
        int sfx = (tid + 1 < 1024) ? part[tid + 1] : 0;
        int sf3 = sfx, sf2 = sfx + h3, sf1 = sf2 + h2, sf0 = sf1 + h1;
        if (sf0 < k && k <= sf0 + h0) { s_tb = tid*4;   s_ca = sf0; }
        if (sf1 < k && k <= sf1 + h1) { s_tb = tid*4+1; s_ca = sf1; }
        if (sf2 < k && k <= sf2 + h2) { s_tb = tid*4+2; s_ca = sf2; }
        if (sf3 < k && k <= sf3 + h3) { s_tb = tid*4+3; s_ca = sf3; }
        __syncthreads();
        int tb = s_tb, kk = k - s_ca;
        if (tid < 256) part[tid] = 0;
        __syncthreads();
        float ssum = 0.f;
        for (int i = tid; i < P; i += TK_THREADS) {
            unsigned key = skeys[i];
            int bin = key >> 20;
            if (bin > tb) ssum += __uint_as_float(key);
            else if (bin == tb) atomicAdd(&part[(key >> 12) & 255u], 1);
        }
        __syncthreads();
        if (tid < 256) {
            int cum = 0;
            for (int b = tid + 1; b < 256; ++b) cum += part[b];
            int h = part[tid];
            if (cum < kk && kk <= cum + h) { s_tb2 = tid; s_ca2 = cum; }
        }
        if (tid == 0) s_cnt = 0;
        __syncthreads();
        int tb2 = s_tb2, kk2 = kk - s_ca2;
        unsigned* ckeys = (unsigned*)hist;
        for (int i = tid; i < P; i += TK_THREADS) {
            unsigned key = skeys[i];
            if ((int)(key >> 20) == tb) {
                int b2 = (key >> 12) & 255u;
                if (b2 > tb2) ssum += __uint_as_float(key);
                else if (b2 == tb2) {
                    int slot = atomicAdd(&s_cnt, 1);
                    if (slot < CK_MAX) ckeys[slot] = key;
                }
            }
        }
        __syncthreads();
        int m = s_cnt; if (m > CK_MAX) m = CK_MAX;
        for (int i = tid; i < m; i += TK_THREADS) {
            unsigned key = ckeys[i];
            int rank = 0;
            for (int j = 0; j < m; ++j) {
                unsigned kj = ckeys[j];
                rank += (kj > key) || (kj == key && j < i);
            }
            if (rank < kk2) ssum += __uint_as_float(key);
        }
        #pragma unroll
        for (int off = 32; off >= 1; off >>= 1) ssum += __shfl_down(ssum, off);
        __syncthreads();
        if ((tid & 63) == 0) shf[tid >> 6] = ssum;
        __syncthreads();
        if (tid == 0) {
            float tot = 0.f;
            for (int i = 0; i < 16; ++i) tot += shf[i];
            bsum = tot;
        }
    }

    if (tid == 0) {
        if (bsum != 0.f) atomicAdd(&acc[2], bsum);
        __threadfence();                              // release acc adds + n_pos store
        unsigned old = atomicAdd(done, 1u);
        if (old == (unsigned)(N - 1)) {               // last block: finalize
            float a0 = atomicAdd(&acc[0], 0.f);       // atomic reads (acquire-ish)
            float a1 = atomicAdd(&acc[1], 0.f);
            float a2 = atomicAdd(&acc[2], 0.f);
            int tot = 0;
            for (int i = 0; i < N; ++i) tot += n_pos[i];
            float npos = (float)tot;
            float conf = (a2 + a1) / npos;
            float loc  = a0 / (4.f * npos);
            float loss = conf + loc;
            unsigned ub = __float_as_uint(loss);
            unsigned r = (ub + 0x7FFFu + ((ub >> 16) & 1u)) >> 16;  // bf16 RNE
            out[0] = (r << 16) | r;
        }
    }
}

extern "C" void kernel_launch(void* const* d_in, const int* in_sizes, int n_in,
                              void* d_out, int out_size, void* d_ws, size_t ws_size,
                              hipStream_t stream) {
    const float* locs   = (const float*)d_in[0];
    const float* scores = (const float*)d_in[1];
    const float* boxes  = (const float*)d_in[2];
    const int*   labels = (const int*)d_in[3];
    const float* priors = (const float*)d_in[4];

    int P = in_sizes[4] / 4;
    long long NPl = in_sizes[0] / 4;
    int N = (int)(NPl / P);
    int C = (int)((long long)in_sizes[1] / NPl);
    int O = in_sizes[3] / N;
    size_t NP = (size_t)N * P;
    int gx = (P + SBLOCK - 1) / SBLOCK;

    char* ws = (char*)d_ws;
    float*    acc    = (float*)ws;     ws += 16;
    unsigned* done   = (unsigned*)ws;  ws += 16;
    int*      n_pos  = (int*)ws;       ws += (size_t)N * 4;
    int*      pfop   = (int*)ws;       ws += (size_t)N * O * 4;
    int*      hcnt   = (int*)ws;       ws += (size_t)N * NBIN * 4;   // contiguous with hsum
    float*    hsum   = (float*)ws;     ws += (size_t)N * NBIN * 4;
    float*    pb_loc = (float*)ws;     ws += (size_t)N * gx * 4;
    float*    pb_pce = (float*)ws;     ws += (size_t)N * gx * 4;
    int*      pb_npos= (int*)ws;       ws += (size_t)N * gx * 4;
    int*      tcarr  = (int*)ws;       ws += NP * 4;
    float*    ce_neg = (float*)ws;     ws += NP * 4;

    long long hlen = (long long)N * NBIN * 2;          // hcnt+hsum dwords to zero
    match_object_kernel<<<N * O, BLOCK, 0, stream>>>(boxes, priors, pfop, acc, n_pos,
                                                     done, hcnt, hlen, N, P, O);
    int npb = 0;
    if (C == 81 && (P % 4) == 0 && O <= MAXO) {
        npb = gx;
        fused_staged_kernel<<<dim3(gx, N), SBLOCK, 0, stream>>>(
            boxes, priors, locs, labels, pfop, scores, ce_neg,
            pb_loc, pb_pce, pb_npos, hcnt, hsum, N, P, O);
    } else {
        int gbx = (P + BLOCK - 1) / BLOCK;
        match_prior_kernel<<<dim3(gbx, N), BLOCK, 0, stream>>>(boxes, priors, locs, labels,
                                                               pfop, tcarr, acc, n_pos, N, P, O);
        loss_generic_kernel<<<(int)((NP + BLOCK - 1) / BLOCK), BLOCK, 0, stream>>>(
            scores, tcarr, ce_neg, acc, (int)NP, C);
    }
    topk_final_kernel<<<N, TK_THREADS, 0, stream>>>(ce_neg, n_pos,
                                                    pb_loc, pb_pce, pb_npos, npb,
                                                    hcnt, hsum,
                                                    acc, done, N, P, (unsigned*)d_out);
}

// Round 9
// 205.605 us; speedup vs baseline: 1.7720x; 1.7720x over previous
//
#include <hip/hip_runtime.h>
#include <hip/hip_bf16.h>
#include <stdint.h>

#define BLOCK 256
#define FB 64              // fused block = 1 wave (22KB LDS -> 7 blocks/CU)
#define MAXO 64
#define TK_THREADS 1024
#define CK_MAX 4096

// ---------------- K1 (FALLBACK PATH ONLY): per-object argmax over P + init ----------------
__global__ void match_object_kernel(const float* __restrict__ boxes,
                                    const float* __restrict__ priors,
                                    int* __restrict__ pfop,
                                    float* __restrict__ acc, int* __restrict__ n_pos,
                                    unsigned* __restrict__ done, int N, int P, int O) {
    __shared__ unsigned long long swm[4];
    int idx = blockIdx.x, tid = threadIdx.x;
    if (idx == 0) {                       // init for later dispatches (stream-ordered)
        for (int j = tid; j < N; j += BLOCK) n_pos[j] = 0;
        if (tid >= 64 && tid < 67) acc[tid - 64] = 0.f;
        if (tid == 96) *done = 0u;
    }
    const float* b = boxes + (size_t)idx * 4;
    float bx0 = b[0], by0 = b[1], bx1 = b[2], by1 = b[3];
    float areaa = (bx1 - bx0) * (by1 - by0);

    unsigned long long best = 0ULL;
    for (int p = tid; p < P; p += BLOCK) {
        float4 pr = ((const float4*)priors)[p];
        float px0 = pr.x - pr.z * 0.5f, py0 = pr.y - pr.w * 0.5f;
        float px1 = pr.x + pr.z * 0.5f, py1 = pr.y + pr.w * 0.5f;
        float areab = (px1 - px0) * (py1 - py0);
        float ltx = fmaxf(bx0, px0), lty = fmaxf(by0, py0);
        float rbx = fminf(bx1, px1), rby = fminf(by1, py1);
        float wx = fmaxf(rbx - ltx, 0.f), wy = fmaxf(rby - lty, 0.f);
        float inter = wx * wy;
        float iou = inter / (areaa + areab - inter);
        unsigned long long cand = (((unsigned long long)__float_as_uint(iou)) << 32) |
                                  (unsigned long long)(0xFFFFFFFFu - (unsigned)p);
        if (cand > best) best = cand;     // larger iou; tie -> smaller p (numpy first)
    }
    #pragma unroll
    for (int off = 32; off >= 1; off >>= 1) {
        unsigned long long other = __shfl_down(best, off);
        if (other > best) best = other;
    }
    if ((tid & 63) == 0) swm[tid >> 6] = best;
    __syncthreads();
    if (tid == 0) {
        unsigned long long r = swm[0];
        for (int w = 1; w < BLOCK / 64; ++w) if (swm[w] > r) r = swm[w];
        pfop[idx] = (int)(0xFFFFFFFFu - (unsigned)(r & 0xFFFFFFFFull));
    }
}

// ---------------- K2+K3 fused v9: R7 LDS-bounce, 64-thread blocks, BASE match only ----------------
// R7 structure (proven 47us), two changes: (1) FB=64 -> 22KB LDS -> 7 blocks/CU
// (was 3): 2.3x more staging streams in flight per CU. (2) forced-match removed
// (pure threshold matching); topk reconstructs forced corrections from pfop it
// computes itself -> the match_object dispatch disappears from the fast path.
// Block (0,0) takes over acc/done init (stream-ordered before topk's atomics).
__global__ void __launch_bounds__(FB)
fused_staged_kernel(const float* __restrict__ boxes,
                    const float* __restrict__ priors,
                    const float* __restrict__ locs,
                    const int* __restrict__ labels,
                    const float* __restrict__ scores,
                    float* __restrict__ ce_neg,
                    float* __restrict__ pb_loc, float* __restrict__ pb_pce,
                    int* __restrict__ pb_npos,
                    float* __restrict__ acc, unsigned* __restrict__ done,
                    int N, int P, int O) {
    __shared__ float4 sstage4[FB * 81 / 4];   // 1296 float4 = 20,736 B
    __shared__ float sbx[MAXO * 4];
    __shared__ int   slab[MAXO];
    const float* sstage = (const float*)sstage4;

    int n = blockIdx.y, bx = blockIdx.x, tid = threadIdx.x;
    if (bx == 0 && n == 0) {                  // init duty (was match_object's)
        if (tid < 3) acc[tid] = 0.f;
        if (tid == 3) *done = 0u;
    }
    int p0 = bx * FB;
    int rows = P - p0; if (rows > FB) rows = FB;   // rows % 4 == 0 (P % 4 == 0)
    int p = p0 + tid;
    bool valid = tid < rows;
    size_t t = (size_t)n * P + p;

    for (int i = tid; i < O * 4; i += FB) sbx[i] = boxes[(size_t)n * O * 4 + i];
    for (int i = tid; i < O; i += FB) slab[i] = labels[n * O + i];
    float4 pr = make_float4(0.f, 0.f, 1.f, 1.f);
    float4 pl = make_float4(0.f, 0.f, 0.f, 0.f);
    if (valid) {
        pr = ((const float4*)priors)[p];
        pl = ((const float4*)locs)[t];
    }

    // stage: coalesced float4 copy, identity layout (chunk is contiguous)
    const float4* chunk = (const float4*)(scores + ((size_t)n * P + p0) * 81);
    if (rows == FB) {
        #pragma unroll
        for (int j = 0; j < 20; ++j)
            sstage4[j * FB + tid] = chunk[j * FB + tid];
        if (tid < 16)                                  // tail: 1280..1295
            sstage4[20 * FB + tid] = chunk[20 * FB + tid];
    } else {                                           // partial tile (one per image)
        int nf4 = rows * 81 / 4;
        for (int j = 0; j < 21; ++j) {
            int idx = j * FB + tid;
            if (idx < nf4) sstage4[idx] = chunk[idx];
        }
    }
    __syncthreads();   // 1-wave block: just a waitcnt

    float my_loc = 0.f, my_pce = 0.f; int my_pos = 0;
    if (valid) {
        const float* row = sstage + tid * 81;          // bank stride 17: conflict-free
        float e = 0.f;
        #pragma unroll
        for (int j = 0; j < 81; ++j) e += __expf(row[j]);

        // BASE match only (no forced): strict > = first index
        float px0 = pr.x - pr.z * 0.5f, py0 = pr.y - pr.w * 0.5f;
        float px1 = pr.x + pr.z * 0.5f, py1 = pr.y + pr.w * 0.5f;
        float areab = (px1 - px0) * (py1 - py0);
        float best = -1.f; int bo = 0;
        for (int o = 0; o < O; ++o) {
            float x0 = sbx[o*4+0], y0 = sbx[o*4+1], x1 = sbx[o*4+2], y1 = sbx[o*4+3];
            float ltx = fmaxf(x0, px0), lty = fmaxf(y0, py0);
            float rbx = fminf(x1, px1), rby = fminf(y1, py1);
            float wx = fmaxf(rbx - ltx, 0.f), wy = fmaxf(rby - lty, 0.f);
            float inter = wx * wy;
            float areao = (x1 - x0) * (y1 - y0);
            float iou = inter / (areao + areab - inter);
            if (iou > best) { best = iou; bo = o; }
        }
        int tc = (best < 0.5f) ? 0 : slab[bo];

        float stc = row[tc];                           // free: already staged
        float ce = logf(e) - stc;
        bool pos = (tc != 0);
        ce_neg[t] = pos ? 0.f : ce;                    // coalesced store
        if (pos) {
            my_pce = ce; my_pos = 1;
            float x0 = sbx[bo*4+0], y0 = sbx[bo*4+1], x1 = sbx[bo*4+2], y1 = sbx[bo*4+3];
            float cx = (x0 + x1) * 0.5f, cy = (y0 + y1) * 0.5f;
            float bw = x1 - x0, bh = y1 - y0;
            float g0 = (cx - pr.x) / (pr.z / 10.0f);
            float g1 = (cy - pr.y) / (pr.w / 10.0f);
            float g2 = logf(bw / pr.z) * 5.0f;
            float g3 = logf(bh / pr.w) * 5.0f;
            my_loc = fabsf(pl.x-g0) + fabsf(pl.y-g1) + fabsf(pl.z-g2) + fabsf(pl.w-g3);
        }
    }

    #pragma unroll
    for (int off = 32; off >= 1; off >>= 1) {
        my_loc += __shfl_down(my_loc, off);
        my_pce += __shfl_down(my_pce, off);
        my_pos += __shfl_down(my_pos, off);
    }
    if (tid == 0) {                                    // plain stores, no atomics
        int npb = gridDim.x;
        pb_loc[n * npb + bx]  = my_loc;
        pb_pce[n * npb + bx]  = my_pce;
        pb_npos[n * npb + bx] = my_pos;
    }
}

// ---------------- fallback K2: per-prior match -> tcarr (any C path) ----------------
__global__ void match_prior_kernel(const float* __restrict__ boxes,
                                   const float* __restrict__ priors,
                                   const float* __restrict__ locs,
                                   const int* __restrict__ labels,
                                   const int* __restrict__ pfop,
                                   int* __restrict__ tcarr,
                                   float* __restrict__ acc, int* __restrict__ n_pos,
                                   int N, int P, int O) {
    __shared__ float sbx[MAXO * 4];
    __shared__ float sarea[MAXO];
    __shared__ int   spf[MAXO];
    __shared__ int   slab[MAXO];
    int n = blockIdx.y, tid = threadIdx.x;
    if (tid < O * 4) sbx[tid] = boxes[(size_t)n * O * 4 + tid];
    if (tid >= 128 && tid < 128 + O) spf[tid - 128]  = pfop[n * O + (tid - 128)];
    if (tid >= 192 && tid < 192 + O) slab[tid - 192] = labels[n * O + (tid - 192)];
    __syncthreads();
    if (tid < O)
        sarea[tid] = (sbx[tid*4+2] - sbx[tid*4+0]) * (sbx[tid*4+3] - sbx[tid*4+1]);
    __syncthreads();

    int p = blockIdx.x * BLOCK + tid;
    bool valid = p < P;
    float my_loc = 0.f; int my_pos = 0;
    if (valid) {
        float4 pr = ((const float4*)priors)[p];
        float px0 = pr.x - pr.z * 0.5f, py0 = pr.y - pr.w * 0.5f;
        float px1 = pr.x + pr.z * 0.5f, py1 = pr.y + pr.w * 0.5f;
        float areab = (px1 - px0) * (py1 - py0);

        float best = -1.f; int bo = 0;
        for (int o = 0; o < O; ++o) {
            float ltx = fmaxf(sbx[o*4+0], px0);
            float lty = fmaxf(sbx[o*4+1], py0);
            float rbx = fminf(sbx[o*4+2], px1);
            float rby = fminf(sbx[o*4+3], py1);
            float wx = fmaxf(rbx - ltx, 0.f), wy = fmaxf(rby - lty, 0.f);
            float inter = wx * wy;
            float iou = inter / (sarea[o] + areab - inter);
            if (iou > best) { best = iou; bo = o; }
        }
        int fo = -1;
        for (int o = 0; o < O; ++o) if (spf[o] == p) fo = o;
        int obj; float ov;
        if (fo >= 0) { obj = fo; ov = 1.0f; }
        else         { obj = bo; ov = best; }
        int lab = slab[obj];
        int tc = (ov < 0.5f) ? 0 : lab;
        tcarr[(size_t)n * P + p] = tc;
        if (tc != 0) {
            my_pos = 1;
            float x0 = sbx[obj*4+0], y0 = sbx[obj*4+1], x1 = sbx[obj*4+2], y1 = sbx[obj*4+3];
            float cx = (x0 + x1) * 0.5f, cy = (y0 + y1) * 0.5f;
            float w = x1 - x0, h = y1 - y0;
            float g0 = (cx - pr.x) / (pr.z / 10.0f);
            float g1 = (cy - pr.y) / (pr.w / 10.0f);
            float g2 = logf(w / pr.z) * 5.0f;
            float g3 = logf(h / pr.w) * 5.0f;
            const float* pl = locs + ((size_t)n * P + p) * 4;
            my_loc = fabsf(pl[0]-g0) + fabsf(pl[1]-g1) + fabsf(pl[2]-g2) + fabsf(pl[3]-g3);
        }
    }
    #pragma unroll
    for (int off = 32; off >= 1; off >>= 1) {
        my_loc += __shfl_down(my_loc, off);
        my_pos += __shfl_down(my_pos, off);
    }
    if ((tid & 63) == 0 && my_pos) {
        atomicAdd(&acc[0], my_loc);
        atomicAdd(&n_pos[n], my_pos);
    }
}

// ---------------- generic fallback (any C) ----------------
__global__ void loss_generic_kernel(const float* __restrict__ scores,
                                    const int* __restrict__ tcarr,
                                    float* __restrict__ ce_neg, float* __restrict__ acc,
                                    int NP, int C) {
    int t = blockIdx.x * blockDim.x + threadIdx.x;
    if (t >= NP) return;
    int tc = tcarr[t];
    const float* s = scores + (size_t)t * C;
    float m = -3.0e38f;
    for (int j = 0; j < C; ++j) m = fmaxf(m, s[j]);
    float l = 0.f, stc = 0.f;
    for (int j = 0; j < C; ++j) {
        float v = s[j];
        l += __expf(v - m);
        if (j == tc) stc = v;
    }
    float ce = m + logf(l) - stc;
    bool pos = (tc != 0);
    ce_neg[t] = pos ? 0.f : ce;
    if (pos) atomicAdd(&acc[1], ce);
}

// ---------------- K4 v3: forced-match prologue + R7 radix top-k + final combine ----------------
// Fast path (npb>0): prologue computes pfop (wave w = object w, exact match_object
// expressions -> bit-identical argmax), applies the <=16 forced corrections per image
// (patch skeys[p*]=0 for was-neg; delta loc/pce/n_pos), then runs the R7 radix
// byte-for-byte on the patched keys. Fallback (npb==0): R7 behavior unchanged.
__global__ void topk_final_kernel(const float* __restrict__ ce_neg,
                                  int* __restrict__ n_pos,
                                  const float* __restrict__ pb_loc,
                                  const float* __restrict__ pb_pce,
                                  const int* __restrict__ pb_npos, int npb,
                                  const float* __restrict__ boxes,
                                  const float* __restrict__ priors,
                                  const float* __restrict__ locs,
                                  const int* __restrict__ labels,
                                  const float* __restrict__ scores,
                                  float* __restrict__ acc, unsigned* __restrict__ done,
                                  int N, int P, int O, unsigned* __restrict__ out) {
    __shared__ unsigned skeys[8732];
    __shared__ int hist[4096];        // aliased as ckeys later
    __shared__ int part[1024];
    __shared__ float sbx_l[64];       // O <= 16 on fast path
    __shared__ int   slab_l[16];
    __shared__ int   spf_l[16];
    __shared__ float sdl[16], sdp[16]; __shared__ int sdn[16];
    __shared__ float s_psl, s_psp; __shared__ int s_psn;
    __shared__ int s_tb, s_ca, s_tb2, s_ca2, s_cnt, s_np;
    __shared__ float shf[16];
    int n = blockIdx.x, tid = threadIdx.x;
    int w = tid >> 6, lane = tid & 63;

    int k;
    if (npb > 0) {
        // stage ce_neg row now (patched below; reused by radix)
        const float* rowg = ce_neg + (size_t)n * P;
        for (int i = tid; i < P; i += TK_THREADS) skeys[i] = __float_as_uint(rowg[i]);
        if (tid < O * 4) sbx_l[tid] = boxes[(size_t)n * O * 4 + tid];
        if (tid >= 64 && tid < 64 + O) slab_l[tid - 64] = labels[n * O + (tid - 64)];
        if (tid >= 128 && tid < 144) { sdl[tid-128] = 0.f; sdp[tid-128] = 0.f; sdn[tid-128] = 0; }
        if (tid < 64) {                                // pb partial reduce (wave 0)
            float psl = 0.f, psp = 0.f; int psn = 0;
            for (int i = tid; i < npb; i += 64) {
                psl += pb_loc[n * npb + i];
                psp += pb_pce[n * npb + i];
                psn += pb_npos[n * npb + i];
            }
            #pragma unroll
            for (int off = 32; off >= 1; off >>= 1) {
                psl += __shfl_down(psl, off);
                psp += __shfl_down(psp, off);
                psn += __shfl_down(psn, off);
            }
            if (tid == 0) { s_psl = psl; s_psp = psp; s_psn = psn; }
        }
        __syncthreads();

        // ---- pfop: wave w = object w, exact match_object expressions ----
        if (w < O) {
            float bx0 = sbx_l[w*4+0], by0 = sbx_l[w*4+1];
            float bx1 = sbx_l[w*4+2], by1 = sbx_l[w*4+3];
            float areaa = (bx1 - bx0) * (by1 - by0);
            unsigned long long best = 0ULL;
            for (int p = lane; p < P; p += 64) {
                float4 pr = ((const float4*)priors)[p];
                float px0 = pr.x - pr.z * 0.5f, py0 = pr.y - pr.w * 0.5f;
                float px1 = pr.x + pr.z * 0.5f, py1 = pr.y + pr.w * 0.5f;
                float areab = (px1 - px0) * (py1 - py0);
                float ltx = fmaxf(bx0, px0), lty = fmaxf(by0, py0);
                float rbx = fminf(bx1, px1), rby = fminf(by1, py1);
                float wx = fmaxf(rbx - ltx, 0.f), wy = fmaxf(rby - lty, 0.f);
                float inter = wx * wy;
                float iou = inter / (areaa + areab - inter);
                unsigned long long cand = (((unsigned long long)__float_as_uint(iou)) << 32) |
                                          (unsigned long long)(0xFFFFFFFFu - (unsigned)p);
                if (cand > best) best = cand;
            }
            #pragma unroll
            for (int off = 32; off >= 1; off >>= 1) {
                unsigned long long o2 = __shfl_down(best, off);
                if (o2 > best) best = o2;
            }
            if (lane == 0) spf_l[w] = (int)(0xFFFFFFFFu - (unsigned)(best & 0xFFFFFFFFull));
        }
        __syncthreads();

        // ---- forced corrections: wave w handles object w; last-o-wins dedupe ----
        if (w < O) {
            int pstar = spf_l[w];
            bool skip = false;
            for (int o2 = w + 1; o2 < O; ++o2) if (spf_l[o2] == pstar) skip = true;
            if (!skip) {
                size_t tstar = (size_t)n * P + pstar;
                float4 prs = ((const float4*)priors)[pstar];     // broadcast
                float px0 = prs.x - prs.z * 0.5f, py0 = prs.y - prs.w * 0.5f;
                float px1 = prs.x + prs.z * 0.5f, py1 = prs.y + prs.w * 0.5f;
                float areab = (px1 - px0) * (py1 - py0);
                unsigned long long bkey = 0ULL;                  // base match, exact fused exprs
                if (lane < O) {
                    float x0 = sbx_l[lane*4+0], y0 = sbx_l[lane*4+1];
                    float x1 = sbx_l[lane*4+2], y1 = sbx_l[lane*4+3];
                    float ltx = fmaxf(x0, px0), lty = fmaxf(y0, py0);
                    float rbx = fminf(x1, px1), rby = fminf(y1, py1);
                    float wx = fmaxf(rbx - ltx, 0.f), wy = fmaxf(rby - lty, 0.f);
                    float inter = wx * wy;
                    float areao = (x1 - x0) * (y1 - y0);
                    float iou = inter / (areao + areab - inter);
                    bkey = (((unsigned long long)__float_as_uint(iou)) << 32) |
                           (unsigned long long)(0xFFFFFFFFu - (unsigned)lane);  // tie -> smaller o
                }
                #pragma unroll
                for (int off = 32; off >= 1; off >>= 1) {
                    unsigned long long o2 = __shfl_down(bkey, off);
                    if (o2 > bkey) bkey = o2;
                }
                const float* srow = scores + tstar * 81;         // row lse (v6 pattern)
                float e = __expf(srow[lane]);
                if (lane < 17) e += __expf(srow[64 + lane]);
                #pragma unroll
                for (int off = 32; off >= 1; off >>= 1) e += __shfl_xor(e, off);
                if (lane == 0) {
                    int bo = (int)(0xFFFFFFFFu - (unsigned)(bkey & 0xFFFFFFFFull));
                    float ov = __uint_as_float((unsigned)(bkey >> 32));
                    int tc_base = (ov < 0.5f) ? 0 : slab_l[bo];
                    int lab = slab_l[w];
                    float l = logf(e);
                    float4 plv = ((const float4*)locs)[tstar];
                    auto locof = [&](int obj) {                  // exact fused loc exprs
                        float x0 = sbx_l[obj*4+0], y0 = sbx_l[obj*4+1];
                        float x1 = sbx_l[obj*4+2], y1 = sbx_l[obj*4+3];
                        float cx = (x0 + x1) * 0.5f, cy = (y0 + y1) * 0.5f;
                        float bw2 = x1 - x0, bh2 = y1 - y0;
                        float g0 = (cx - prs.x) / (prs.z / 10.0f);
                        float g1 = (cy - prs.y) / (prs.w / 10.0f);
                        float g2 = logf(bw2 / prs.z) * 5.0f;
                        float g3 = logf(bh2 / prs.w) * 5.0f;
                        return fabsf(plv.x-g0)+fabsf(plv.y-g1)+fabsf(plv.z-g2)+fabsf(plv.w-g3);
                    };
                    if (lab != 0) {
                        float ce_new = l - srow[lab];
                        float ln = locof(w);
                        if (tc_base != 0) {                      // was pos -> swap obj
                            float ce_old = l - srow[tc_base];
                            float lo = locof(bo);
                            sdl[w] = ln - lo; sdp[w] = ce_new - ce_old; sdn[w] = 0;
                        } else {                                 // was neg -> now pos
                            skeys[pstar] = 0u;                   // exact 0.0f, pre-histogram
                            sdl[w] = ln; sdp[w] = ce_new; sdn[w] = 1;
                        }
                    } else if (tc_base != 0) {                   // degenerate forced label 0
                        float ce_old = l - srow[tc_base];
                        float lo = locof(bo);
                        skeys[pstar] = __float_as_uint(l - srow[0]);
                        sdl[w] = -lo; sdp[w] = -ce_old; sdn[w] = -1;
                    }
                }
            }
        }
        __syncthreads();
        if (tid == 0) {
            float dl = 0.f, dp = 0.f; int dn = 0;
            for (int i = 0; i < 16; ++i) { dl += sdl[i]; dp += sdp[i]; dn += sdn[i]; }
            int np2 = s_psn + dn;
            s_np = np2;
            n_pos[n] = np2;                            // plain store; fenced before done++
            float a0v = s_psl + dl, a1v = s_psp + dp;
            if (a0v != 0.f) atomicAdd(&acc[0], a0v);
            if (a1v != 0.f) atomicAdd(&acc[1], a1v);
        }
        __syncthreads();
        k = 3 * s_np;
    } else {
        k = 3 * n_pos[n];
    }
    if (k > P) k = P;
    float bsum = 0.f;

    if (k > 0) {                                      // R7 radix, byte-for-byte
        if (npb == 0) {                                // fast path already staged+patched
            const float* row = ce_neg + (size_t)n * P;
            for (int i = tid; i < P; i += TK_THREADS) skeys[i] = __float_as_uint(row[i]);
        }
        #pragma unroll
        for (int b = 0; b < 4; ++b) hist[tid * 4 + b] = 0;
        __syncthreads();

        for (int i = tid; i < P; i += TK_THREADS) atomicAdd(&hist[skeys[i] >> 20], 1);
        __syncthreads();
        int h0 = hist[tid*4], h1 = hist[tid*4+1], h2 = hist[tid*4+2], h3 = hist[tid*4+3];
        part[tid] = h0 + h1 + h2 + h3;
        __syncthreads();
        for (int s = 1; s < 1024; s <<= 1) {
            int v = part[tid] + ((tid + s < 1024) ? part[tid + s] : 0);
            __syncthreads();
            part[tid] = v;
            __syncthreads();
        }
        int sfx = (tid + 1 < 1024) ? part[tid + 1] : 0;
        int sf3 = sfx, sf2 = sfx + h3, sf1 = sf2 + h2, sf0 = sf1 + h1;
        if (sf0 < k && k <= sf0 + h0) { s_tb = tid*4;   s_ca = sf0; }
        if (sf1 < k && k <= sf1 + h1) { s_tb = tid*4+1; s_ca = sf1; }
        if (sf2 < k && k <= sf2 + h2) { s_tb = tid*4+2; s_ca = sf2; }
        if (sf3 < k && k <= sf3 + h3) { s_tb = tid*4+3; s_ca = sf3; }
        __syncthreads();
        int tb = s_tb, kk = k - s_ca;

        if (tid < 256) part[tid] = 0;
        __syncthreads();
        float ssum = 0.f;
        for (int i = tid; i < P; i += TK_THREADS) {
            unsigned key = skeys[i];
            int bin = key >> 20;
            if (bin > tb) ssum += __uint_as_float(key);
            else if (bin == tb) atomicAdd(&part[(key >> 12) & 255u], 1);
        }
        __syncthreads();
        if (tid < 256) {
            int cum = 0;
            for (int b = tid + 1; b < 256; ++b) cum += part[b];
            int h = part[tid];
            if (cum < kk && kk <= cum + h) { s_tb2 = tid; s_ca2 = cum; }
        }
        if (tid == 0) s_cnt = 0;
        __syncthreads();
        int tb2 = s_tb2, kk2 = kk - s_ca2;

        unsigned* ckeys = (unsigned*)hist;
        for (int i = tid; i < P; i += TK_THREADS) {
            unsigned key = skeys[i];
            if ((int)(key >> 20) == tb) {
                int b2 = (key >> 12) & 255u;
                if (b2 > tb2) ssum += __uint_as_float(key);
                else if (b2 == tb2) {
                    int slot = atomicAdd(&s_cnt, 1);
                    if (slot < CK_MAX) ckeys[slot] = key;
                }
            }
        }
        __syncthreads();
        int m = s_cnt; if (m > CK_MAX) m = CK_MAX;
        for (int i = tid; i < m; i += TK_THREADS) {
            unsigned key = ckeys[i];
            int rank = 0;
            for (int j = 0; j < m; ++j) {
                unsigned kj = ckeys[j];
                rank += (kj > key) || (kj == key && j < i);
            }
            if (rank < kk2) ssum += __uint_as_float(key);
        }
        #pragma unroll
        for (int off = 32; off >= 1; off >>= 1) ssum += __shfl_down(ssum, off);
        __syncthreads();
        if ((tid & 63) == 0) shf[tid >> 6] = ssum;
        __syncthreads();
        float tot = 0.f;
        for (int i = 0; i < 16; ++i) tot += shf[i];
        bsum = tot;
    }

    if (tid == 0) {
        if (bsum != 0.f) atomicAdd(&acc[2], bsum);
        __threadfence();                              // release acc adds + n_pos store
        unsigned old = atomicAdd(done, 1u);
        if (old == (unsigned)(N - 1)) {               // last block: finalize
            float a0 = atomicAdd(&acc[0], 0.f);       // atomic reads (acquire-ish)
            float a1 = atomicAdd(&acc[1], 0.f);
            float a2 = atomicAdd(&acc[2], 0.f);
            int tot = 0;
            for (int i = 0; i < N; ++i) tot += n_pos[i];
            float npos = (float)tot;
            float conf = (a2 + a1) / npos;
            float loc  = a0 / (4.f * npos);
            float loss = conf + loc;
            unsigned ub = __float_as_uint(loss);
            unsigned r = (ub + 0x7FFFu + ((ub >> 16) & 1u)) >> 16;  // bf16 RNE
            out[0] = (r << 16) | r;
        }
    }
}

extern "C" void kernel_launch(void* const* d_in, const int* in_sizes, int n_in,
                              void* d_out, int out_size, void* d_ws, size_t ws_size,
                              hipStream_t stream) {
    const float* locs   = (const float*)d_in[0];
    const float* scores = (const float*)d_in[1];
    const float* boxes  = (const float*)d_in[2];
    const int*   labels = (const int*)d_in[3];
    const float* priors = (const float*)d_in[4];

    int P = in_sizes[4] / 4;
    long long NPl = in_sizes[0] / 4;
    int N = (int)(NPl / P);
    int C = (int)((long long)in_sizes[1] / NPl);
    int O = in_sizes[3] / N;
    size_t NP = (size_t)N * P;
    int gx = (P + FB - 1) / FB;

    char* ws = (char*)d_ws;
    float*    acc    = (float*)ws;     ws += 16;
    unsigned* done   = (unsigned*)ws;  ws += 16;
    int*      n_pos  = (int*)ws;       ws += (size_t)N * 4;
    int*      pfop   = (int*)ws;       ws += (size_t)N * O * 4;
    float*    pb_loc = (float*)ws;     ws += (size_t)N * gx * 4;
    float*    pb_pce = (float*)ws;     ws += (size_t)N * gx * 4;
    int*      pb_npos= (int*)ws;       ws += (size_t)N * gx * 4;
    int*      tcarr  = (int*)ws;       ws += NP * 4;
    float*    ce_neg = (float*)ws;     ws += NP * 4;

    int npb = 0;
    if (C == 81 && (P % 4) == 0 && O <= 16) {
        npb = gx;                                      // 2 dispatches total
        fused_staged_kernel<<<dim3(gx, N), FB, 0, stream>>>(
            boxes, priors, locs, labels, scores, ce_neg,
            pb_loc, pb_pce, pb_npos, acc, done, N, P, O);
    } else {                                           // fallback: old 3-dispatch chain
        match_object_kernel<<<N * O, BLOCK, 0, stream>>>(boxes, priors, pfop, acc, n_pos,
                                                         done, N, P, O);
        int gbx = (P + BLOCK - 1) / BLOCK;
        match_prior_kernel<<<dim3(gbx, N), BLOCK, 0, stream>>>(boxes, priors, locs, labels,
                                                               pfop, tcarr, acc, n_pos, N, P, O);
        loss_generic_kernel<<<(int)((NP + BLOCK - 1) / BLOCK), BLOCK, 0, stream>>>(
            scores, tcarr, ce_neg, acc, (int)NP, C);
    }
    topk_final_kernel<<<N, TK_THREADS, 0, stream>>>(ce_neg, n_pos,
                                                    pb_loc, pb_pce, pb_npos, npb,
                                                    boxes, priors, locs, labels, scores,
                                                    acc, done, N, P, O, (unsigned*)d_out);
}

// Round 10
// 193.424 us; speedup vs baseline: 1.8836x; 1.0630x over previous
//
#include <hip/hip_runtime.h>
#include <hip/hip_bf16.h>
#include <stdint.h>

#define BLOCK 256
#define SBLOCK 128
#define MAXO 64
#define TK_THREADS 1024
#define CK_MAX 4096

// ---------------- K1: per-object argmax over P (block per (n,o)) + init ----------------
__global__ void match_object_kernel(const float* __restrict__ boxes,
                                    const float* __restrict__ priors,
                                    int* __restrict__ pfop,
                                    float* __restrict__ acc, int* __restrict__ n_pos,
                                    unsigned* __restrict__ done, int N, int P, int O) {
    __shared__ unsigned long long swm[4];
    int idx = blockIdx.x, tid = threadIdx.x;
    if (idx == 0) {                       // init for later dispatches (stream-ordered)
        for (int j = tid; j < N; j += BLOCK) n_pos[j] = 0;
        if (tid >= 64 && tid < 67) acc[tid - 64] = 0.f;
        if (tid == 96) *done = 0u;
    }
    const float* b = boxes + (size_t)idx * 4;
    float bx0 = b[0], by0 = b[1], bx1 = b[2], by1 = b[3];
    float areaa = (bx1 - bx0) * (by1 - by0);

    unsigned long long best = 0ULL;
    for (int p = tid; p < P; p += BLOCK) {
        float4 pr = ((const float4*)priors)[p];
        float px0 = pr.x - pr.z * 0.5f, py0 = pr.y - pr.w * 0.5f;
        float px1 = pr.x + pr.z * 0.5f, py1 = pr.y + pr.w * 0.5f;
        float areab = (px1 - px0) * (py1 - py0);
        float ltx = fmaxf(bx0, px0), lty = fmaxf(by0, py0);
        float rbx = fminf(bx1, px1), rby = fminf(by1, py1);
        float wx = fmaxf(rbx - ltx, 0.f), wy = fmaxf(rby - lty, 0.f);
        float inter = wx * wy;
        float iou = inter / (areaa + areab - inter);
        unsigned long long cand = (((unsigned long long)__float_as_uint(iou)) << 32) |
                                  (unsigned long long)(0xFFFFFFFFu - (unsigned)p);
        if (cand > best) best = cand;     // larger iou; tie -> smaller p (numpy first)
    }
    #pragma unroll
    for (int off = 32; off >= 1; off >>= 1) {
        unsigned long long other = __shfl_down(best, off);
        if (other > best) best = other;
    }
    if ((tid & 63) == 0) swm[tid >> 6] = best;
    __syncthreads();
    if (tid == 0) {
        unsigned long long r = swm[0];
        for (int w = 1; w < BLOCK / 64; ++w) if (swm[w] > r) r = swm[w];
        pfop[idx] = (int)(0xFFFFFFFFu - (unsigned)(r & 0xFFFFFFFFull));
    }
}

// ---------------- K2+K3 fused v7 (R7 exact, proven 47us): LDS-bounce, thread-per-row ----------------
__global__ void __launch_bounds__(SBLOCK)
fused_staged_kernel(const float* __restrict__ boxes,
                    const float* __restrict__ priors,
                    const float* __restrict__ locs,
                    const int* __restrict__ labels,
                    const int* __restrict__ pfop,
                    const float* __restrict__ scores,
                    float* __restrict__ ce_neg,
                    float* __restrict__ pb_loc, float* __restrict__ pb_pce,
                    int* __restrict__ pb_npos,
                    int N, int P, int O) {
    __shared__ float4 sstage4[SBLOCK * 81 / 4];   // 2592 float4 = 41,472 B
    __shared__ float sbx[MAXO * 4];
    __shared__ int   spf[MAXO];
    __shared__ int   slab[MAXO];
    __shared__ float sl[2], sp[2]; __shared__ int sn[2];
    const float* sstage = (const float*)sstage4;

    int n = blockIdx.y, bx = blockIdx.x, tid = threadIdx.x;
    int w = tid >> 6, lane = tid & 63;
    int p0 = bx * SBLOCK;
    int rows = P - p0; if (rows > SBLOCK) rows = SBLOCK;   // rows % 4 == 0 (P % 4 == 0)
    int p = p0 + tid;
    bool valid = tid < rows;
    size_t t = (size_t)n * P + p;

    // ---- metadata -> LDS (small), prior/loc -> regs ----
    for (int i = tid; i < O * 4; i += SBLOCK) sbx[i] = boxes[(size_t)n * O * 4 + i];
    for (int i = tid; i < O; i += SBLOCK) { spf[i] = pfop[n * O + i]; slab[i] = labels[n * O + i]; }
    float4 pr = make_float4(0.f, 0.f, 1.f, 1.f);
    float4 pl = make_float4(0.f, 0.f, 0.f, 0.f);
    if (valid) {
        pr = ((const float4*)priors)[p];
        pl = ((const float4*)locs)[t];
    }

    // ---- stage: coalesced float4 copy, identity layout (global chunk is contiguous) ----
    const float4* chunk = (const float4*)(scores + ((size_t)n * P + p0) * 81);
    if (rows == SBLOCK) {
        #pragma unroll
        for (int j = 0; j < 20; ++j)
            sstage4[j * SBLOCK + tid] = chunk[j * SBLOCK + tid];
        if (tid < 32)                                  // tail: 2560..2591
            sstage4[20 * SBLOCK + tid] = chunk[20 * SBLOCK + tid];
    } else {                                           // partial tile (one per image)
        int nf4 = rows * 81 / 4;
        for (int j = 0; j < 21; ++j) {
            int idx = j * SBLOCK + tid;
            if (idx < nf4) sstage4[idx] = chunk[idx];
        }
    }
    __syncthreads();

    // ---- consume: thread-per-row from LDS ----
    float my_loc = 0.f, my_pce = 0.f; int my_pos = 0;
    if (valid) {
        const float* row = sstage + tid * 81;          // bank stride 17: conflict-free
        float e = 0.f;
        #pragma unroll
        for (int j = 0; j < 81; ++j) e += __expf(row[j]);

        // match (v2 semantics): strict > = first index; forced match last-wins
        float px0 = pr.x - pr.z * 0.5f, py0 = pr.y - pr.w * 0.5f;
        float px1 = pr.x + pr.z * 0.5f, py1 = pr.y + pr.w * 0.5f;
        float areab = (px1 - px0) * (py1 - py0);
        float best = -1.f; int bo = 0;
        for (int o = 0; o < O; ++o) {                  // sbx reads wave-broadcast
            float x0 = sbx[o*4+0], y0 = sbx[o*4+1], x1 = sbx[o*4+2], y1 = sbx[o*4+3];
            float ltx = fmaxf(x0, px0), lty = fmaxf(y0, py0);
            float rbx = fminf(x1, px1), rby = fminf(y1, py1);
            float wx = fmaxf(rbx - ltx, 0.f), wy = fmaxf(rby - lty, 0.f);
            float inter = wx * wy;
            float areao = (x1 - x0) * (y1 - y0);
            float iou = inter / (areao + areab - inter);
            if (iou > best) { best = iou; bo = o; }
        }
        int fo = -1;
        for (int o = 0; o < O; ++o) if (spf[o] == p) fo = o;
        int obj; float ov;
        if (fo >= 0) { obj = fo; ov = 1.0f; }
        else         { obj = bo; ov = best; }
        int tc = (ov < 0.5f) ? 0 : slab[obj];

        float stc = row[tc];                           // free: already staged
        float ce = logf(e) - stc;
        bool pos = (tc != 0);
        ce_neg[t] = pos ? 0.f : ce;                    // coalesced store
        if (pos) {
            my_pce = ce; my_pos = 1;
            float x0 = sbx[obj*4+0], y0 = sbx[obj*4+1], x1 = sbx[obj*4+2], y1 = sbx[obj*4+3];
            float cx = (x0 + x1) * 0.5f, cy = (y0 + y1) * 0.5f;
            float bw = x1 - x0, bh = y1 - y0;
            float g0 = (cx - pr.x) / (pr.z / 10.0f);
            float g1 = (cy - pr.y) / (pr.w / 10.0f);
            float g2 = logf(bw / pr.z) * 5.0f;
            float g3 = logf(bh / pr.w) * 5.0f;
            my_loc = fabsf(pl.x-g0) + fabsf(pl.y-g1) + fabsf(pl.z-g2) + fabsf(pl.w-g3);
        }
    }

    // ---- block partials: plain stores, no atomics ----
    #pragma unroll
    for (int off = 32; off >= 1; off >>= 1) {
        my_loc += __shfl_down(my_loc, off);
        my_pce += __shfl_down(my_pce, off);
        my_pos += __shfl_down(my_pos, off);
    }
    if (lane == 0) { sl[w] = my_loc; sp[w] = my_pce; sn[w] = my_pos; }
    __syncthreads();
    if (tid == 0) {
        int npb = gridDim.x;
        pb_loc[n * npb + bx]  = sl[0] + sl[1];
        pb_pce[n * npb + bx]  = sp[0] + sp[1];
        pb_npos[n * npb + bx] = sn[0] + sn[1];
    }
}

// ---------------- fallback K2: per-prior match -> tcarr (any C path) ----------------
__global__ void match_prior_kernel(const float* __restrict__ boxes,
                                   const float* __restrict__ priors,
                                   const float* __restrict__ locs,
                                   const int* __restrict__ labels,
                                   const int* __restrict__ pfop,
                                   int* __restrict__ tcarr,
                                   float* __restrict__ acc, int* __restrict__ n_pos,
                                   int N, int P, int O) {
    __shared__ float sbx[MAXO * 4];
    __shared__ float sarea[MAXO];
    __shared__ int   spf[MAXO];
    __shared__ int   slab[MAXO];
    int n = blockIdx.y, tid = threadIdx.x;
    if (tid < O * 4) sbx[tid] = boxes[(size_t)n * O * 4 + tid];
    if (tid >= 128 && tid < 128 + O) spf[tid - 128]  = pfop[n * O + (tid - 128)];
    if (tid >= 192 && tid < 192 + O) slab[tid - 192] = labels[n * O + (tid - 192)];
    __syncthreads();
    if (tid < O)
        sarea[tid] = (sbx[tid*4+2] - sbx[tid*4+0]) * (sbx[tid*4+3] - sbx[tid*4+1]);
    __syncthreads();

    int p = blockIdx.x * BLOCK + tid;
    bool valid = p < P;
    float my_loc = 0.f; int my_pos = 0;
    if (valid) {
        float4 pr = ((const float4*)priors)[p];
        float px0 = pr.x - pr.z * 0.5f, py0 = pr.y - pr.w * 0.5f;
        float px1 = pr.x + pr.z * 0.5f, py1 = pr.y + pr.w * 0.5f;
        float areab = (px1 - px0) * (py1 - py0);

        float best = -1.f; int bo = 0;
        for (int o = 0; o < O; ++o) {
            float ltx = fmaxf(sbx[o*4+0], px0);
            float lty = fmaxf(sbx[o*4+1], py0);
            float rbx = fminf(sbx[o*4+2], px1);
            float rby = fminf(sbx[o*4+3], py1);
            float wx = fmaxf(rbx - ltx, 0.f), wy = fmaxf(rby - lty, 0.f);
            float inter = wx * wy;
            float iou = inter / (sarea[o] + areab - inter);
            if (iou > best) { best = iou; bo = o; }
        }
        int fo = -1;
        for (int o = 0; o < O; ++o) if (spf[o] == p) fo = o;
        int obj; float ov;
        if (fo >= 0) { obj = fo; ov = 1.0f; }
        else         { obj = bo; ov = best; }
        int lab = slab[obj];
        int tc = (ov < 0.5f) ? 0 : lab;
        tcarr[(size_t)n * P + p] = tc;
        if (tc != 0) {
            my_pos = 1;
            float x0 = sbx[obj*4+0], y0 = sbx[obj*4+1], x1 = sbx[obj*4+2], y1 = sbx[obj*4+3];
            float cx = (x0 + x1) * 0.5f, cy = (y0 + y1) * 0.5f;
            float w = x1 - x0, h = y1 - y0;
            float g0 = (cx - pr.x) / (pr.z / 10.0f);
            float g1 = (cy - pr.y) / (pr.w / 10.0f);
            float g2 = logf(w / pr.z) * 5.0f;
            float g3 = logf(h / pr.w) * 5.0f;
            const float* pl = locs + ((size_t)n * P + p) * 4;
            my_loc = fabsf(pl[0]-g0) + fabsf(pl[1]-g1) + fabsf(pl[2]-g2) + fabsf(pl[3]-g3);
        }
    }
    #pragma unroll
    for (int off = 32; off >= 1; off >>= 1) {
        my_loc += __shfl_down(my_loc, off);
        my_pos += __shfl_down(my_pos, off);
    }
    if ((tid & 63) == 0 && my_pos) {
        atomicAdd(&acc[0], my_loc);
        atomicAdd(&n_pos[n], my_pos);
    }
}

// ---------------- generic fallback (any C) ----------------
__global__ void loss_generic_kernel(const float* __restrict__ scores,
                                    const int* __restrict__ tcarr,
                                    float* __restrict__ ce_neg, float* __restrict__ acc,
                                    int NP, int C) {
    int t = blockIdx.x * blockDim.x + threadIdx.x;
    if (t >= NP) return;
    int tc = tcarr[t];
    const float* s = scores + (size_t)t * C;
    float m = -3.0e38f;
    for (int j = 0; j < C; ++j) m = fmaxf(m, s[j]);
    float l = 0.f, stc = 0.f;
    for (int j = 0; j < C; ++j) {
        float v = s[j];
        l += __expf(v - m);
        if (j == tc) stc = v;
    }
    float ce = m + logf(l) - stc;
    bool pos = (tc != 0);
    ce_neg[t] = pos ? 0.f : ce;
    if (pos) atomicAdd(&acc[1], ce);
}

// ---------------- K4 v4: R7 radix with (a) wave-aggregated histogram fused into the
// staging pass (one atomic per DISTINCT bin per wave instead of 64-way serialized
// same-address LDS RMWs) and (b) shuffle suffix-scan (2 barriers, was 20). Algorithm,
// tie semantics, and float summation order unchanged from the passing R7 code. ----------------
__global__ void topk_final_kernel(const float* __restrict__ ce_neg,
                                  int* __restrict__ n_pos,
                                  const float* __restrict__ pb_loc,
                                  const float* __restrict__ pb_pce,
                                  const int* __restrict__ pb_npos, int npb,
                                  float* __restrict__ acc, unsigned* __restrict__ done,
                                  int N, int P, unsigned* __restrict__ out) {
    __shared__ unsigned skeys[8732];
    __shared__ int hist[4096];        // aliased as ckeys later
    __shared__ int part[256];
    __shared__ int wtot[16];
    __shared__ int s_tb, s_ca, s_tb2, s_ca2, s_cnt, s_np;
    __shared__ float shf[16];
    int n = blockIdx.x, tid = threadIdx.x;
    int w = tid >> 6, lane = tid & 63;

    int k;
    if (npb > 0) {                    // fused path: reduce per-block partials (wave 0)
        if (tid < 64) {
            float psl = 0.f, psp = 0.f; int psn = 0;
            for (int i = tid; i < npb; i += 64) {
                psl += pb_loc[n * npb + i];
                psp += pb_pce[n * npb + i];
                psn += pb_npos[n * npb + i];
            }
            #pragma unroll
            for (int off = 32; off >= 1; off >>= 1) {
                psl += __shfl_down(psl, off);
                psp += __shfl_down(psp, off);
                psn += __shfl_down(psn, off);
            }
            if (tid == 0) {
                s_np = psn;
                n_pos[n] = psn;                       // plain store; fenced before done++
                if (psl != 0.f) atomicAdd(&acc[0], psl);
                if (psp != 0.f) atomicAdd(&acc[1], psp);
            }
        }
        __syncthreads();
        k = 3 * s_np;
    } else {
        k = 3 * n_pos[n];
    }
    if (k > P) k = P;
    float bsum = 0.f;

    if (k > 0) {                                      // block-uniform
        const float* row = ce_neg + (size_t)n * P;
        #pragma unroll
        for (int b = 0; b < 4; ++b) hist[tid * 4 + b] = 0;
        __syncthreads();

        // ---- pass 1 (fused stage + wave-aggregated histogram) ----
        for (int i = tid; i < P; i += TK_THREADS) {
            unsigned key = __float_as_uint(row[i]);
            skeys[i] = key;
            int bin = (int)(key >> 20);
            unsigned long long todo = __ballot(1);     // active lanes this iteration
            while (todo) {
                int leader = __builtin_ctzll(todo);
                int lbin = __shfl(bin, leader);
                unsigned long long same = __ballot(bin == lbin) & todo;
                if (lane == leader)
                    atomicAdd(&hist[lbin], (int)__builtin_popcountll(same));
                todo &= ~same;
            }
        }
        __syncthreads();

        // ---- threshold bin: shuffle suffix-scan (replaces 20-barrier 1024-scan) ----
        int h0 = hist[tid*4], h1 = hist[tid*4+1], h2 = hist[tid*4+2], h3 = hist[tid*4+3];
        int lsum = h0 + h1 + h2 + h3;
        int si = lsum;
        #pragma unroll
        for (int off = 1; off < 64; off <<= 1) {       // inclusive suffix within wave
            int tv = __shfl_down(si, off);
            if (lane + off < 64) si += tv;
        }
        if (lane == 0) wtot[w] = si;                   // wave totals
        __syncthreads();
        if (tid < 16) {                                // wave 0: exclusive suffix of 16
            int ov = wtot[tid];
            int v = ov;
            #pragma unroll
            for (int off = 1; off < 16; off <<= 1) {
                int tv = __shfl_down(v, off);
                if (lane + off < 16) v += tv;
            }
            wtot[tid] = v - ov;
        }
        __syncthreads();
        int sfx = wtot[w] + (si - lsum);               // == old part[tid+1]
        int sf3 = sfx, sf2 = sfx + h3, sf1 = sf2 + h2, sf0 = sf1 + h1;
        if (sf0 < k && k <= sf0 + h0) { s_tb = tid*4;   s_ca = sf0; }
        if (sf1 < k && k <= sf1 + h1) { s_tb = tid*4+1; s_ca = sf1; }
        if (sf2 < k && k <= sf2 + h2) { s_tb = tid*4+2; s_ca = sf2; }
        if (sf3 < k && k <= sf3 + h3) { s_tb = tid*4+3; s_ca = sf3; }
        __syncthreads();
        int tb = s_tb, kk = k - s_ca;

        if (tid < 256) part[tid] = 0;
        __syncthreads();
        float ssum = 0.f;
        for (int i = tid; i < P; i += TK_THREADS) {
            unsigned key = skeys[i];
            int bin = key >> 20;
            if (bin > tb) ssum += __uint_as_float(key);
            else if (bin == tb) atomicAdd(&part[(key >> 12) & 255u], 1);
        }
        __syncthreads();
        if (tid < 256) {
            int cum = 0;
            for (int b = tid + 1; b < 256; ++b) cum += part[b];
            int h = part[tid];
            if (cum < kk && kk <= cum + h) { s_tb2 = tid; s_ca2 = cum; }
        }
        if (tid == 0) s_cnt = 0;
        __syncthreads();
        int tb2 = s_tb2, kk2 = kk - s_ca2;

        unsigned* ckeys = (unsigned*)hist;
        for (int i = tid; i < P; i += TK_THREADS) {
            unsigned key = skeys[i];
            if ((int)(key >> 20) == tb) {
                int b2 = (key >> 12) & 255u;
                if (b2 > tb2) ssum += __uint_as_float(key);
                else if (b2 == tb2) {
                    int slot = atomicAdd(&s_cnt, 1);
                    if (slot < CK_MAX) ckeys[slot] = key;
                }
            }
        }
        __syncthreads();
        int m = s_cnt; if (m > CK_MAX) m = CK_MAX;
        for (int i = tid; i < m; i += TK_THREADS) {
            unsigned key = ckeys[i];
            int rank = 0;
            for (int j = 0; j < m; ++j) {
                unsigned kj = ckeys[j];
                rank += (kj > key) || (kj == key && j < i);
            }
            if (rank < kk2) ssum += __uint_as_float(key);
        }
        #pragma unroll
        for (int off = 32; off >= 1; off >>= 1) ssum += __shfl_down(ssum, off);
        __syncthreads();
        if ((tid & 63) == 0) shf[tid >> 6] = ssum;
        __syncthreads();
        float tot = 0.f;
        for (int i = 0; i < 16; ++i) tot += shf[i];
        bsum = tot;
    }

    if (tid == 0) {
        if (bsum != 0.f) atomicAdd(&acc[2], bsum);
        __threadfence();                              // release acc adds + n_pos store
        unsigned old = atomicAdd(done, 1u);
        if (old == (unsigned)(N - 1)) {               // last block: finalize
            float a0 = atomicAdd(&acc[0], 0.f);       // atomic reads (acquire-ish)
            float a1 = atomicAdd(&acc[1], 0.f);
            float a2 = atomicAdd(&acc[2], 0.f);
            int tot = 0;
            for (int i = 0; i < N; ++i) tot += n_pos[i];
            float npos = (float)tot;
            float conf = (a2 + a1) / npos;
            float loc  = a0 / (4.f * npos);
            float loss = conf + loc;
            unsigned ub = __float_as_uint(loss);
            unsigned r = (ub + 0x7FFFu + ((ub >> 16) & 1u)) >> 16;  // bf16 RNE
            out[0] = (r << 16) | r;
        }
    }
}

extern "C" void kernel_launch(void* const* d_in, const int* in_sizes, int n_in,
                              void* d_out, int out_size, void* d_ws, size_t ws_size,
                              hipStream_t stream) {
    const float* locs   = (const float*)d_in[0];
    const float* scores = (const float*)d_in[1];
    const float* boxes  = (const float*)d_in[2];
    const int*   labels = (const int*)d_in[3];
    const float* priors = (const float*)d_in[4];

    int P = in_sizes[4] / 4;
    long long NPl = in_sizes[0] / 4;
    int N = (int)(NPl / P);
    int C = (int)((long long)in_sizes[1] / NPl);
    int O = in_sizes[3] / N;
    size_t NP = (size_t)N * P;
    int gx = (P + SBLOCK - 1) / SBLOCK;

    char* ws = (char*)d_ws;
    float*    acc    = (float*)ws;     ws += 16;
    unsigned* done   = (unsigned*)ws;  ws += 16;
    int*      n_pos  = (int*)ws;       ws += (size_t)N * 4;
    int*      pfop   = (int*)ws;       ws += (size_t)N * O * 4;
    float*    pb_loc = (float*)ws;     ws += (size_t)N * gx * 4;
    float*    pb_pce = (float*)ws;     ws += (size_t)N * gx * 4;
    int*      pb_npos= (int*)ws;       ws += (size_t)N * gx * 4;
    int*      tcarr  = (int*)ws;       ws += NP * 4;
    float*    ce_neg = (float*)ws;     ws += NP * 4;

    match_object_kernel<<<N * O, BLOCK, 0, stream>>>(boxes, priors, pfop, acc, n_pos,
                                                     done, N, P, O);
    int npb = 0;
    if (C == 81 && (P % 4) == 0 && O <= MAXO) {
        npb = gx;
        fused_staged_kernel<<<dim3(gx, N), SBLOCK, 0, stream>>>(
            boxes, priors, locs, labels, pfop, scores, ce_neg,
            pb_loc, pb_pce, pb_npos, N, P, O);
    } else {
        int gbx = (P + BLOCK - 1) / BLOCK;
        match_prior_kernel<<<dim3(gbx, N), BLOCK, 0, stream>>>(boxes, priors, locs, labels,
                                                               pfop, tcarr, acc, n_pos, N, P, O);
        loss_generic_kernel<<<(int)((NP + BLOCK - 1) / BLOCK), BLOCK, 0, stream>>>(
            scores, tcarr, ce_neg, acc, (int)NP, C);
    }
    topk_final_kernel<<<N, TK_THREADS, 0, stream>>>(ce_neg, n_pos,
                                                    pb_loc, pb_pce, pb_npos, npb,
                                                    acc, done, N, P, (unsigned*)d_out);
}

// Round 11
// 189.625 us; speedup vs baseline: 1.9213x; 1.0200x over previous
//
#include <hip/hip_runtime.h>
#include <hip/hip_bf16.h>
#include <stdint.h>

#define BLOCK 256
#define TPB 128            // fused threads per block
#define SROWS 96           // fused rows per block: 31.1KB LDS -> 5 blocks/CU (was 128 -> 3)
#define MAXO 64
#define TK_THREADS 1024
#define CK_MAX 4096

// ---------------- K1: per-object argmax over P (block per (n,o)) + init ----------------
__global__ void match_object_kernel(const float* __restrict__ boxes,
                                    const float* __restrict__ priors,
                                    int* __restrict__ pfop,
                                    float* __restrict__ acc, int* __restrict__ n_pos,
                                    unsigned* __restrict__ done, int N, int P, int O) {
    __shared__ unsigned long long swm[4];
    int idx = blockIdx.x, tid = threadIdx.x;
    if (idx == 0) {                       // init for later dispatches (stream-ordered)
        for (int j = tid; j < N; j += BLOCK) n_pos[j] = 0;
        if (tid >= 64 && tid < 67) acc[tid - 64] = 0.f;
        if (tid == 96) *done = 0u;
    }
    const float* b = boxes + (size_t)idx * 4;
    float bx0 = b[0], by0 = b[1], bx1 = b[2], by1 = b[3];
    float areaa = (bx1 - bx0) * (by1 - by0);

    unsigned long long best = 0ULL;
    for (int p = tid; p < P; p += BLOCK) {
        float4 pr = ((const float4*)priors)[p];
        float px0 = pr.x - pr.z * 0.5f, py0 = pr.y - pr.w * 0.5f;
        float px1 = pr.x + pr.z * 0.5f, py1 = pr.y + pr.w * 0.5f;
        float areab = (px1 - px0) * (py1 - py0);
        float ltx = fmaxf(bx0, px0), lty = fmaxf(by0, py0);
        float rbx = fminf(bx1, px1), rby = fminf(by1, py1);
        float wx = fmaxf(rbx - ltx, 0.f), wy = fmaxf(rby - lty, 0.f);
        float inter = wx * wy;
        float iou = inter / (areaa + areab - inter);
        unsigned long long cand = (((unsigned long long)__float_as_uint(iou)) << 32) |
                                  (unsigned long long)(0xFFFFFFFFu - (unsigned)p);
        if (cand > best) best = cand;     // larger iou; tie -> smaller p (numpy first)
    }
    #pragma unroll
    for (int off = 32; off >= 1; off >>= 1) {
        unsigned long long other = __shfl_down(best, off);
        if (other > best) best = other;
    }
    if ((tid & 63) == 0) swm[tid >> 6] = best;
    __syncthreads();
    if (tid == 0) {
        unsigned long long r = swm[0];
        for (int w = 1; w < BLOCK / 64; ++w) if (swm[w] > r) r = swm[w];
        pfop[idx] = (int)(0xFFFFFFFFu - (unsigned)(r & 0xFFFFFFFFull));
    }
}

// ---------------- K2+K3 fused (R7 structure, SROWS=96): LDS-bounce, thread-per-row ----------------
// R7 proved this structure at 47us with SROWS=128 (43.5KB LDS -> 3 blocks/CU -> 1.5
// waves/SIMD; latency-bound, compute floor ~5us, BW floor ~15us). Single change this
// round: SROWS=96 -> 31.1KB LDS -> 5 blocks/CU = 10 waves/CU (+67% TLP) at the cost
// of 25% idle lanes in consume (96/128). All arithmetic identical, same order.
__global__ void __launch_bounds__(TPB)
fused_staged_kernel(const float* __restrict__ boxes,
                    const float* __restrict__ priors,
                    const float* __restrict__ locs,
                    const int* __restrict__ labels,
                    const int* __restrict__ pfop,
                    const float* __restrict__ scores,
                    float* __restrict__ ce_neg,
                    float* __restrict__ pb_loc, float* __restrict__ pb_pce,
                    int* __restrict__ pb_npos,
                    int N, int P, int O) {
    __shared__ float4 sstage4[SROWS * 81 / 4];   // 1944 float4 = 31,104 B
    __shared__ float sbx[MAXO * 4];
    __shared__ int   spf[MAXO];
    __shared__ int   slab[MAXO];
    __shared__ float sl[2], sp[2]; __shared__ int sn[2];
    const float* sstage = (const float*)sstage4;

    int n = blockIdx.y, bx = blockIdx.x, tid = threadIdx.x;
    int w = tid >> 6, lane = tid & 63;
    int p0 = bx * SROWS;
    int rows = P - p0; if (rows > SROWS) rows = SROWS;   // rows % 4 == 0 (P % 4 == 0)
    int p = p0 + tid;
    bool valid = tid < rows;
    size_t t = (size_t)n * P + p;

    // ---- metadata -> LDS (small), prior/loc -> regs ----
    for (int i = tid; i < O * 4; i += TPB) sbx[i] = boxes[(size_t)n * O * 4 + i];
    for (int i = tid; i < O; i += TPB) { spf[i] = pfop[n * O + i]; slab[i] = labels[n * O + i]; }
    float4 pr = make_float4(0.f, 0.f, 1.f, 1.f);
    float4 pl = make_float4(0.f, 0.f, 0.f, 0.f);
    if (valid) {
        pr = ((const float4*)priors)[p];
        pl = ((const float4*)locs)[t];
    }

    // ---- stage: coalesced float4 copy, identity layout (global chunk is contiguous) ----
    const float4* chunk = (const float4*)(scores + ((size_t)n * P + p0) * 81);
    if (rows == SROWS) {                               // 1944 = 15*128 + 24
        #pragma unroll
        for (int j = 0; j < 15; ++j)                   // idx max 1919 < 1944: unconditional
            sstage4[j * TPB + tid] = chunk[j * TPB + tid];
        if (tid < 24)                                  // tail: 1920..1943
            sstage4[15 * TPB + tid] = chunk[15 * TPB + tid];
    } else {                                           // partial tile (one per image)
        int nf4 = rows * 81 / 4;
        for (int j = 0; j < 16; ++j) {
            int idx = j * TPB + tid;
            if (idx < nf4) sstage4[idx] = chunk[idx];
        }
    }
    __syncthreads();

    // ---- consume: thread-per-row from LDS ----
    float my_loc = 0.f, my_pce = 0.f; int my_pos = 0;
    if (valid) {
        const float* row = sstage + tid * 81;          // bank stride 17: conflict-free
        float e = 0.f;
        #pragma unroll
        for (int j = 0; j < 81; ++j) e += __expf(row[j]);

        // match (v2 semantics): strict > = first index; forced match last-wins
        float px0 = pr.x - pr.z * 0.5f, py0 = pr.y - pr.w * 0.5f;
        float px1 = pr.x + pr.z * 0.5f, py1 = pr.y + pr.w * 0.5f;
        float areab = (px1 - px0) * (py1 - py0);
        float best = -1.f; int bo = 0;
        for (int o = 0; o < O; ++o) {                  // sbx reads wave-broadcast
            float x0 = sbx[o*4+0], y0 = sbx[o*4+1], x1 = sbx[o*4+2], y1 = sbx[o*4+3];
            float ltx = fmaxf(x0, px0), lty = fmaxf(y0, py0);
            float rbx = fminf(x1, px1), rby = fminf(y1, py1);
            float wx = fmaxf(rbx - ltx, 0.f), wy = fmaxf(rby - lty, 0.f);
            float inter = wx * wy;
            float areao = (x1 - x0) * (y1 - y0);
            float iou = inter / (areao + areab - inter);
            if (iou > best) { best = iou; bo = o; }
        }
        int fo = -1;
        for (int o = 0; o < O; ++o) if (spf[o] == p) fo = o;
        int obj; float ov;
        if (fo >= 0) { obj = fo; ov = 1.0f; }
        else         { obj = bo; ov = best; }
        int tc = (ov < 0.5f) ? 0 : slab[obj];

        float stc = row[tc];                           // free: already staged
        float ce = logf(e) - stc;
        bool pos = (tc != 0);
        ce_neg[t] = pos ? 0.f : ce;                    // coalesced store
        if (pos) {
            my_pce = ce; my_pos = 1;
            float x0 = sbx[obj*4+0], y0 = sbx[obj*4+1], x1 = sbx[obj*4+2], y1 = sbx[obj*4+3];
            float cx = (x0 + x1) * 0.5f, cy = (y0 + y1) * 0.5f;
            float bw = x1 - x0, bh = y1 - y0;
            float g0 = (cx - pr.x) / (pr.z / 10.0f);
            float g1 = (cy - pr.y) / (pr.w / 10.0f);
            float g2 = logf(bw / pr.z) * 5.0f;
            float g3 = logf(bh / pr.w) * 5.0f;
            my_loc = fabsf(pl.x-g0) + fabsf(pl.y-g1) + fabsf(pl.z-g2) + fabsf(pl.w-g3);
        }
    }

    // ---- block partials: plain stores, no atomics ----
    #pragma unroll
    for (int off = 32; off >= 1; off >>= 1) {
        my_loc += __shfl_down(my_loc, off);
        my_pce += __shfl_down(my_pce, off);
        my_pos += __shfl_down(my_pos, off);
    }
    if (lane == 0) { sl[w] = my_loc; sp[w] = my_pce; sn[w] = my_pos; }
    __syncthreads();
    if (tid == 0) {
        int npb = gridDim.x;
        pb_loc[n * npb + bx]  = sl[0] + sl[1];
        pb_pce[n * npb + bx]  = sp[0] + sp[1];
        pb_npos[n * npb + bx] = sn[0] + sn[1];
    }
}

// ---------------- fallback K2: per-prior match -> tcarr (any C path) ----------------
__global__ void match_prior_kernel(const float* __restrict__ boxes,
                                   const float* __restrict__ priors,
                                   const float* __restrict__ locs,
                                   const int* __restrict__ labels,
                                   const int* __restrict__ pfop,
                                   int* __restrict__ tcarr,
                                   float* __restrict__ acc, int* __restrict__ n_pos,
                                   int N, int P, int O) {
    __shared__ float sbx[MAXO * 4];
    __shared__ float sarea[MAXO];
    __shared__ int   spf[MAXO];
    __shared__ int   slab[MAXO];
    int n = blockIdx.y, tid = threadIdx.x;
    if (tid < O * 4) sbx[tid] = boxes[(size_t)n * O * 4 + tid];
    if (tid >= 128 && tid < 128 + O) spf[tid - 128]  = pfop[n * O + (tid - 128)];
    if (tid >= 192 && tid < 192 + O) slab[tid - 192] = labels[n * O + (tid - 192)];
    __syncthreads();
    if (tid < O)
        sarea[tid] = (sbx[tid*4+2] - sbx[tid*4+0]) * (sbx[tid*4+3] - sbx[tid*4+1]);
    __syncthreads();

    int p = blockIdx.x * BLOCK + tid;
    bool valid = p < P;
    float my_loc = 0.f; int my_pos = 0;
    if (valid) {
        float4 pr = ((const float4*)priors)[p];
        float px0 = pr.x - pr.z * 0.5f, py0 = pr.y - pr.w * 0.5f;
        float px1 = pr.x + pr.z * 0.5f, py1 = pr.y + pr.w * 0.5f;
        float areab = (px1 - px0) * (py1 - py0);

        float best = -1.f; int bo = 0;
        for (int o = 0; o < O; ++o) {
            float ltx = fmaxf(sbx[o*4+0], px0);
            float lty = fmaxf(sbx[o*4+1], py0);
            float rbx = fminf(sbx[o*4+2], px1);
            float rby = fminf(sbx[o*4+3], py1);
            float wx = fmaxf(rbx - ltx, 0.f), wy = fmaxf(rby - lty, 0.f);
            float inter = wx * wy;
            float iou = inter / (sarea[o] + areab - inter);
            if (iou > best) { best = iou; bo = o; }
        }
        int fo = -1;
        for (int o = 0; o < O; ++o) if (spf[o] == p) fo = o;
        int obj; float ov;
        if (fo >= 0) { obj = fo; ov = 1.0f; }
        else         { obj = bo; ov = best; }
        int lab = slab[obj];
        int tc = (ov < 0.5f) ? 0 : lab;
        tcarr[(size_t)n * P + p] = tc;
        if (tc != 0) {
            my_pos = 1;
            float x0 = sbx[obj*4+0], y0 = sbx[obj*4+1], x1 = sbx[obj*4+2], y1 = sbx[obj*4+3];
            float cx = (x0 + x1) * 0.5f, cy = (y0 + y1) * 0.5f;
            float w = x1 - x0, h = y1 - y0;
            float g0 = (cx - pr.x) / (pr.z / 10.0f);
            float g1 = (cy - pr.y) / (pr.w / 10.0f);
            float g2 = logf(w / pr.z) * 5.0f;
            float g3 = logf(h / pr.w) * 5.0f;
            const float* pl = locs + ((size_t)n * P + p) * 4;
            my_loc = fabsf(pl[0]-g0) + fabsf(pl[1]-g1) + fabsf(pl[2]-g2) + fabsf(pl[3]-g3);
        }
    }
    #pragma unroll
    for (int off = 32; off >= 1; off >>= 1) {
        my_loc += __shfl_down(my_loc, off);
        my_pos += __shfl_down(my_pos, off);
    }
    if ((tid & 63) == 0 && my_pos) {
        atomicAdd(&acc[0], my_loc);
        atomicAdd(&n_pos[n], my_pos);
    }
}

// ---------------- generic fallback (any C) ----------------
__global__ void loss_generic_kernel(const float* __restrict__ scores,
                                    const int* __restrict__ tcarr,
                                    float* __restrict__ ce_neg, float* __restrict__ acc,
                                    int NP, int C) {
    int t = blockIdx.x * blockDim.x + threadIdx.x;
    if (t >= NP) return;
    int tc = tcarr[t];
    const float* s = scores + (size_t)t * C;
    float m = -3.0e38f;
    for (int j = 0; j < C; ++j) m = fmaxf(m, s[j]);
    float l = 0.f, stc = 0.f;
    for (int j = 0; j < C; ++j) {
        float v = s[j];
        l += __expf(v - m);
        if (j == tc) stc = v;
    }
    float ce = m + logf(l) - stc;
    bool pos = (tc != 0);
    ce_neg[t] = pos ? 0.f : ce;
    if (pos) atomicAdd(&acc[1], ce);
}

// ---------------- K4: R7-exact top-k sum per row + partial-reduce + final combine ----------------
__global__ void topk_final_kernel(const float* __restrict__ ce_neg,
                                  int* __restrict__ n_pos,
                                  const float* __restrict__ pb_loc,
                                  const float* __restrict__ pb_pce,
                                  const int* __restrict__ pb_npos, int npb,
                                  float* __restrict__ acc, unsigned* __restrict__ done,
                                  int N, int P, unsigned* __restrict__ out) {
    __shared__ unsigned skeys[8732];
    __shared__ int hist[4096];        // aliased as ckeys later
    __shared__ int part[1024];
    __shared__ int s_tb, s_ca, s_tb2, s_ca2, s_cnt, s_np;
    __shared__ float shf[16];
    int n = blockIdx.x, tid = threadIdx.x;

    int k;
    if (npb > 0) {                    // fused path: reduce per-block partials (wave 0)
        if (tid < 64) {
            float psl = 0.f, psp = 0.f; int psn = 0;
            for (int i = tid; i < npb; i += 64) {
                psl += pb_loc[n * npb + i];
                psp += pb_pce[n * npb + i];
                psn += pb_npos[n * npb + i];
            }
            #pragma unroll
            for (int off = 32; off >= 1; off >>= 1) {
                psl += __shfl_down(psl, off);
                psp += __shfl_down(psp, off);
                psn += __shfl_down(psn, off);
            }
            if (tid == 0) {
                s_np = psn;
                n_pos[n] = psn;                       // plain store; fenced before done++
                if (psl != 0.f) atomicAdd(&acc[0], psl);
                if (psp != 0.f) atomicAdd(&acc[1], psp);
            }
        }
        __syncthreads();
        k = 3 * s_np;
    } else {
        k = 3 * n_pos[n];
    }
    if (k > P) k = P;
    float bsum = 0.f;

    if (k > 0) {                                      // block-uniform
        const float* row = ce_neg + (size_t)n * P;
        for (int i = tid; i < P; i += TK_THREADS) skeys[i] = __float_as_uint(row[i]);
        #pragma unroll
        for (int b = 0; b < 4; ++b) hist[tid * 4 + b] = 0;
        __syncthreads();

        for (int i = tid; i < P; i += TK_THREADS) atomicAdd(&hist[skeys[i] >> 20], 1);
        __syncthreads();
        int h0 = hist[tid*4], h1 = hist[tid*4+1], h2 = hist[tid*4+2], h3 = hist[tid*4+3];
        part[tid] = h0 + h1 + h2 + h3;
        __syncthreads();
        for (int s = 1; s < 1024; s <<= 1) {
            int v = part[tid] + ((tid + s < 1024) ? part[tid + s] : 0);
            __syncthreads();
            part[tid] = v;
            __syncthreads();
        }
        int sfx = (tid + 1 < 1024) ? part[tid + 1] : 0;
        int sf3 = sfx, sf2 = sfx + h3, sf1 = sf2 + h2, sf0 = sf1 + h1;
        if (sf0 < k && k <= sf0 + h0) { s_tb = tid*4;   s_ca = sf0; }
        if (sf1 < k && k <= sf1 + h1) { s_tb = tid*4+1; s_ca = sf1; }
        if (sf2 < k && k <= sf2 + h2) { s_tb = tid*4+2; s_ca = sf2; }
        if (sf3 < k && k <= sf3 + h3) { s_tb = tid*4+3; s_ca = sf3; }
        __syncthreads();
        int tb = s_tb, kk = k - s_ca;

        if (tid < 256) part[tid] = 0;
        __syncthreads();
        float ssum = 0.f;
        for (int i = tid; i < P; i += TK_THREADS) {
            unsigned key = skeys[i];
            int bin = key >> 20;
            if (bin > tb) ssum += __uint_as_float(key);
            else if (bin == tb) atomicAdd(&part[(key >> 12) & 255u], 1);
        }
        __syncthreads();
        if (tid < 256) {
            int cum = 0;
            for (int b = tid + 1; b < 256; ++b) cum += part[b];
            int h = part[tid];
            if (cum < kk && kk <= cum + h) { s_tb2 = tid; s_ca2 = cum; }
        }
        if (tid == 0) s_cnt = 0;
        __syncthreads();
        int tb2 = s_tb2, kk2 = kk - s_ca2;

        unsigned* ckeys = (unsigned*)hist;
        for (int i = tid; i < P; i += TK_THREADS) {
            unsigned key = skeys[i];
            if ((int)(key >> 20) == tb) {
                int b2 = (key >> 12) & 255u;
                if (b2 > tb2) ssum += __uint_as_float(key);
                else if (b2 == tb2) {
                    int slot = atomicAdd(&s_cnt, 1);
                    if (slot < CK_MAX) ckeys[slot] = key;
                }
            }
        }
        __syncthreads();
        int m = s_cnt; if (m > CK_MAX) m = CK_MAX;
        for (int i = tid; i < m; i += TK_THREADS) {
            unsigned key = ckeys[i];
            int rank = 0;
            for (int j = 0; j < m; ++j) {
                unsigned kj = ckeys[j];
                rank += (kj > key) || (kj == key && j < i);
            }
            if (rank < kk2) ssum += __uint_as_float(key);
        }
        #pragma unroll
        for (int off = 32; off >= 1; off >>= 1) ssum += __shfl_down(ssum, off);
        __syncthreads();
        if ((tid & 63) == 0) shf[tid >> 6] = ssum;
        __syncthreads();
        float tot = 0.f;
        for (int i = 0; i < 16; ++i) tot += shf[i];
        bsum = tot;
    }

    if (tid == 0) {
        if (bsum != 0.f) atomicAdd(&acc[2], bsum);
        __threadfence();                              // release acc adds + n_pos store
        unsigned old = atomicAdd(done, 1u);
        if (old == (unsigned)(N - 1)) {               // last block: finalize
            float a0 = atomicAdd(&acc[0], 0.f);       // atomic reads (acquire-ish)
            float a1 = atomicAdd(&acc[1], 0.f);
            float a2 = atomicAdd(&acc[2], 0.f);
            int tot = 0;
            for (int i = 0; i < N; ++i) tot += n_pos[i];
            float npos = (float)tot;
            float conf = (a2 + a1) / npos;
            float loc  = a0 / (4.f * npos);
            float loss = conf + loc;
            unsigned ub = __float_as_uint(loss);
            unsigned r = (ub + 0x7FFFu + ((ub >> 16) & 1u)) >> 16;  // bf16 RNE
            out[0] = (r << 16) | r;
        }
    }
}

extern "C" void kernel_launch(void* const* d_in, const int* in_sizes, int n_in,
                              void* d_out, int out_size, void* d_ws, size_t ws_size,
                              hipStream_t stream) {
    const float* locs   = (const float*)d_in[0];
    const float* scores = (const float*)d_in[1];
    const float* boxes  = (const float*)d_in[2];
    const int*   labels = (const int*)d_in[3];
    const float* priors = (const float*)d_in[4];

    int P = in_sizes[4] / 4;
    long long NPl = in_sizes[0] / 4;
    int N = (int)(NPl / P);
    int C = (int)((long long)in_sizes[1] / NPl);
    int O = in_sizes[3] / N;
    size_t NP = (size_t)N * P;
    int gx = (P + SROWS - 1) / SROWS;

    char* ws = (char*)d_ws;
    float*    acc    = (float*)ws;     ws += 16;
    unsigned* done   = (unsigned*)ws;  ws += 16;
    int*      n_pos  = (int*)ws;       ws += (size_t)N * 4;
    int*      pfop   = (int*)ws;       ws += (size_t)N * O * 4;
    float*    pb_loc = (float*)ws;     ws += (size_t)N * gx * 4;
    float*    pb_pce = (float*)ws;     ws += (size_t)N * gx * 4;
    int*      pb_npos= (int*)ws;       ws += (size_t)N * gx * 4;
    int*      tcarr  = (int*)ws;       ws += NP * 4;
    float*    ce_neg = (float*)ws;     ws += NP * 4;

    match_object_kernel<<<N * O, BLOCK, 0, stream>>>(boxes, priors, pfop, acc, n_pos,
                                                     done, N, P, O);
    int npb = 0;
    if (C == 81 && (P % 4) == 0 && O <= MAXO) {
        npb = gx;
        fused_staged_kernel<<<dim3(gx, N), TPB, 0, stream>>>(
            boxes, priors, locs, labels, pfop, scores, ce_neg,
            pb_loc, pb_pce, pb_npos, N, P, O);
    } else {
        int gbx = (P + BLOCK - 1) / BLOCK;
        match_prior_kernel<<<dim3(gbx, N), BLOCK, 0, stream>>>(boxes, priors, locs, labels,
                                                               pfop, tcarr, acc, n_pos, N, P, O);
        loss_generic_kernel<<<(int)((NP + BLOCK - 1) / BLOCK), BLOCK, 0, stream>>>(
            scores, tcarr, ce_neg, acc, (int)NP, C);
    }
    topk_final_kernel<<<N, TK_THREADS, 0, stream>>>(ce_neg, n_pos,
                                                    pb_loc, pb_pce, pb_npos, npb,
                                                    acc, done, N, P, (unsigned*)d_out);
}

// Round 12
// 184.994 us; speedup vs baseline: 1.9694x; 1.0250x over previous
//
#include <hip/hip_runtime.h>
#include <hip/hip_bf16.h>
#include <stdint.h>

#define BLOCK 256
#define SBLOCK 128
#define MAXO 64
#define TK_THREADS 1024
#define CK_MAX 4096

// ---------------- K1: per-object argmax over P (block per (n,o)) + init ----------------
__global__ void match_object_kernel(const float* __restrict__ boxes,
                                    const float* __restrict__ priors,
                                    int* __restrict__ pfop,
                                    float* __restrict__ acc, int* __restrict__ n_pos,
                                    unsigned* __restrict__ done, int N, int P, int O) {
    __shared__ unsigned long long swm[4];
    int idx = blockIdx.x, tid = threadIdx.x;
    if (idx == 0) {                       // init for later dispatches (stream-ordered)
        for (int j = tid; j < N; j += BLOCK) n_pos[j] = 0;
        if (tid >= 64 && tid < 67) acc[tid - 64] = 0.f;
        if (tid == 96) *done = 0u;
    }
    const float* b = boxes + (size_t)idx * 4;
    float bx0 = b[0], by0 = b[1], bx1 = b[2], by1 = b[3];
    float areaa = (bx1 - bx0) * (by1 - by0);

    unsigned long long best = 0ULL;
    for (int p = tid; p < P; p += BLOCK) {
        float4 pr = ((const float4*)priors)[p];
        float px0 = pr.x - pr.z * 0.5f, py0 = pr.y - pr.w * 0.5f;
        float px1 = pr.x + pr.z * 0.5f, py1 = pr.y + pr.w * 0.5f;
        float areab = (px1 - px0) * (py1 - py0);
        float ltx = fmaxf(bx0, px0), lty = fmaxf(by0, py0);
        float rbx = fminf(bx1, px1), rby = fminf(by1, py1);
        float wx = fmaxf(rbx - ltx, 0.f), wy = fmaxf(rby - lty, 0.f);
        float inter = wx * wy;
        float iou = inter / (areaa + areab - inter);
        unsigned long long cand = (((unsigned long long)__float_as_uint(iou)) << 32) |
                                  (unsigned long long)(0xFFFFFFFFu - (unsigned)p);
        if (cand > best) best = cand;     // larger iou; tie -> smaller p (numpy first)
    }
    #pragma unroll
    for (int off = 32; off >= 1; off >>= 1) {
        unsigned long long other = __shfl_down(best, off);
        if (other > best) best = other;
    }
    if ((tid & 63) == 0) swm[tid >> 6] = best;
    __syncthreads();
    if (tid == 0) {
        unsigned long long r = swm[0];
        for (int w = 1; w < BLOCK / 64; ++w) if (swm[w] > r) r = swm[w];
        pfop[idx] = (int)(0xFFFFFFFFu - (unsigned)(r & 0xFFFFFFFFull));
    }
}

// ---------------- K2+K3 fused (R7 exact): LDS-bounce staging, thread-per-row consume ----------------
__global__ void __launch_bounds__(SBLOCK)
fused_staged_kernel(const float* __restrict__ boxes,
                    const float* __restrict__ priors,
                    const float* __restrict__ locs,
                    const int* __restrict__ labels,
                    const int* __restrict__ pfop,
                    const float* __restrict__ scores,
                    float* __restrict__ ce_neg,
                    float* __restrict__ pb_loc, float* __restrict__ pb_pce,
                    int* __restrict__ pb_npos,
                    int N, int P, int O) {
    __shared__ float4 sstage4[SBLOCK * 81 / 4];   // 2592 float4 = 41,472 B
    __shared__ float sbx[MAXO * 4];
    __shared__ int   spf[MAXO];
    __shared__ int   slab[MAXO];
    __shared__ float sl[2], sp[2]; __shared__ int sn[2];
    const float* sstage = (const float*)sstage4;

    int n = blockIdx.y, bx = blockIdx.x, tid = threadIdx.x;
    int w = tid >> 6, lane = tid & 63;
    int p0 = bx * SBLOCK;
    int rows = P - p0; if (rows > SBLOCK) rows = SBLOCK;   // rows % 4 == 0 (P % 4 == 0)
    int p = p0 + tid;
    bool valid = tid < rows;
    size_t t = (size_t)n * P + p;

    // ---- metadata -> LDS (small), prior/loc -> regs ----
    for (int i = tid; i < O * 4; i += SBLOCK) sbx[i] = boxes[(size_t)n * O * 4 + i];
    for (int i = tid; i < O; i += SBLOCK) { spf[i] = pfop[n * O + i]; slab[i] = labels[n * O + i]; }
    float4 pr = make_float4(0.f, 0.f, 1.f, 1.f);
    float4 pl = make_float4(0.f, 0.f, 0.f, 0.f);
    if (valid) {
        pr = ((const float4*)priors)[p];
        pl = ((const float4*)locs)[t];
    }

    // ---- stage: coalesced float4 copy, identity layout (global chunk is contiguous) ----
    const float4* chunk = (const float4*)(scores + ((size_t)n * P + p0) * 81);
    if (rows == SBLOCK) {
        #pragma unroll
        for (int j = 0; j < 20; ++j)
            sstage4[j * SBLOCK + tid] = chunk[j * SBLOCK + tid];
        if (tid < 32)                                  // tail: 2560..2591
            sstage4[20 * SBLOCK + tid] = chunk[20 * SBLOCK + tid];
    } else {                                           // partial tile (one per image)
        int nf4 = rows * 81 / 4;
        for (int j = 0; j < 21; ++j) {
            int idx = j * SBLOCK + tid;
            if (idx < nf4) sstage4[idx] = chunk[idx];
        }
    }
    __syncthreads();

    // ---- consume: thread-per-row from LDS ----
    float my_loc = 0.f, my_pce = 0.f; int my_pos = 0;
    if (valid) {
        const float* row = sstage + tid * 81;          // bank stride 17: conflict-free
        float e = 0.f;
        #pragma unroll
        for (int j = 0; j < 81; ++j) e += __expf(row[j]);

        // match (v2 semantics): strict > = first index; forced match last-wins
        float px0 = pr.x - pr.z * 0.5f, py0 = pr.y - pr.w * 0.5f;
        float px1 = pr.x + pr.z * 0.5f, py1 = pr.y + pr.w * 0.5f;
        float areab = (px1 - px0) * (py1 - py0);
        float best = -1.f; int bo = 0;
        for (int o = 0; o < O; ++o) {                  // sbx reads wave-broadcast
            float x0 = sbx[o*4+0], y0 = sbx[o*4+1], x1 = sbx[o*4+2], y1 = sbx[o*4+3];
            float ltx = fmaxf(x0, px0), lty = fmaxf(y0, py0);
            float rbx = fminf(x1, px1), rby = fminf(y1, py1);
            float wx = fmaxf(rbx - ltx, 0.f), wy = fmaxf(rby - lty, 0.f);
            float inter = wx * wy;
            float areao = (x1 - x0) * (y1 - y0);
            float iou = inter / (areao + areab - inter);
            if (iou > best) { best = iou; bo = o; }
        }
        int fo = -1;
        for (int o = 0; o < O; ++o) if (spf[o] == p) fo = o;
        int obj; float ov;
        if (fo >= 0) { obj = fo; ov = 1.0f; }
        else         { obj = bo; ov = best; }
        int tc = (ov < 0.5f) ? 0 : slab[obj];

        float stc = row[tc];                           // free: already staged
        float ce = logf(e) - stc;
        bool pos = (tc != 0);
        ce_neg[t] = pos ? 0.f : ce;                    // coalesced store
        if (pos) {
            my_pce = ce; my_pos = 1;
            float x0 = sbx[obj*4+0], y0 = sbx[obj*4+1], x1 = sbx[obj*4+2], y1 = sbx[obj*4+3];
            float cx = (x0 + x1) * 0.5f, cy = (y0 + y1) * 0.5f;
            float bw = x1 - x0, bh = y1 - y0;
            float g0 = (cx - pr.x) / (pr.z / 10.0f);
            float g1 = (cy - pr.y) / (pr.w / 10.0f);
            float g2 = logf(bw / pr.z) * 5.0f;
            float g3 = logf(bh / pr.w) * 5.0f;
            my_loc = fabsf(pl.x-g0) + fabsf(pl.y-g1) + fabsf(pl.z-g2) + fabsf(pl.w-g3);
        }
    }

    // ---- block partials: plain stores, no atomics ----
    #pragma unroll
    for (int off = 32; off >= 1; off >>= 1) {
        my_loc += __shfl_down(my_loc, off);
        my_pce += __shfl_down(my_pce, off);
        my_pos += __shfl_down(my_pos, off);
    }
    if (lane == 0) { sl[w] = my_loc; sp[w] = my_pce; sn[w] = my_pos; }
    __syncthreads();
    if (tid == 0) {
        int npb = gridDim.x;
        pb_loc[n * npb + bx]  = sl[0] + sl[1];
        pb_pce[n * npb + bx]  = sp[0] + sp[1];
        pb_npos[n * npb + bx] = sn[0] + sn[1];
    }
}

// ---------------- fallback K2: per-prior match -> tcarr (any C path) ----------------
__global__ void match_prior_kernel(const float* __restrict__ boxes,
                                   const float* __restrict__ priors,
                                   const float* __restrict__ locs,
                                   const int* __restrict__ labels,
                                   const int* __restrict__ pfop,
                                   int* __restrict__ tcarr,
                                   float* __restrict__ acc, int* __restrict__ n_pos,
                                   int N, int P, int O) {
    __shared__ float sbx[MAXO * 4];
    __shared__ float sarea[MAXO];
    __shared__ int   spf[MAXO];
    __shared__ int   slab[MAXO];
    int n = blockIdx.y, tid = threadIdx.x;
    if (tid < O * 4) sbx[tid] = boxes[(size_t)n * O * 4 + tid];
    if (tid >= 128 && tid < 128 + O) spf[tid - 128]  = pfop[n * O + (tid - 128)];
    if (tid >= 192 && tid < 192 + O) slab[tid - 192] = labels[n * O + (tid - 192)];
    __syncthreads();
    if (tid < O)
        sarea[tid] = (sbx[tid*4+2] - sbx[tid*4+0]) * (sbx[tid*4+3] - sbx[tid*4+1]);
    __syncthreads();

    int p = blockIdx.x * BLOCK + tid;
    bool valid = p < P;
    float my_loc = 0.f; int my_pos = 0;
    if (valid) {
        float4 pr = ((const float4*)priors)[p];
        float px0 = pr.x - pr.z * 0.5f, py0 = pr.y - pr.w * 0.5f;
        float px1 = pr.x + pr.z * 0.5f, py1 = pr.y + pr.w * 0.5f;
        float areab = (px1 - px0) * (py1 - py0);

        float best = -1.f; int bo = 0;
        for (int o = 0; o < O; ++o) {
            float ltx = fmaxf(sbx[o*4+0], px0);
            float lty = fmaxf(sbx[o*4+1], py0);
            float rbx = fminf(sbx[o*4+2], px1);
            float rby = fminf(sbx[o*4+3], py1);
            float wx = fmaxf(rbx - ltx, 0.f), wy = fmaxf(rby - lty, 0.f);
            float inter = wx * wy;
            float iou = inter / (sarea[o] + areab - inter);
            if (iou > best) { best = iou; bo = o; }
        }
        int fo = -1;
        for (int o = 0; o < O; ++o) if (spf[o] == p) fo = o;
        int obj; float ov;
        if (fo >= 0) { obj = fo; ov = 1.0f; }
        else         { obj = bo; ov = best; }
        int lab = slab[obj];
        int tc = (ov < 0.5f) ? 0 : lab;
        tcarr[(size_t)n * P + p] = tc;
        if (tc != 0) {
            my_pos = 1;
            float x0 = sbx[obj*4+0], y0 = sbx[obj*4+1], x1 = sbx[obj*4+2], y1 = sbx[obj*4+3];
            float cx = (x0 + x1) * 0.5f, cy = (y0 + y1) * 0.5f;
            float w = x1 - x0, h = y1 - y0;
            float g0 = (cx - pr.x) / (pr.z / 10.0f);
            float g1 = (cy - pr.y) / (pr.w / 10.0f);
            float g2 = logf(w / pr.z) * 5.0f;
            float g3 = logf(h / pr.w) * 5.0f;
            const float* pl = locs + ((size_t)n * P + p) * 4;
            my_loc = fabsf(pl[0]-g0) + fabsf(pl[1]-g1) + fabsf(pl[2]-g2) + fabsf(pl[3]-g3);
        }
    }
    #pragma unroll
    for (int off = 32; off >= 1; off >>= 1) {
        my_loc += __shfl_down(my_loc, off);
        my_pos += __shfl_down(my_pos, off);
    }
    if ((tid & 63) == 0 && my_pos) {
        atomicAdd(&acc[0], my_loc);
        atomicAdd(&n_pos[n], my_pos);
    }
}

// ---------------- generic fallback (any C) ----------------
__global__ void loss_generic_kernel(const float* __restrict__ scores,
                                    const int* __restrict__ tcarr,
                                    float* __restrict__ ce_neg, float* __restrict__ acc,
                                    int NP, int C) {
    int t = blockIdx.x * blockDim.x + threadIdx.x;
    if (t >= NP) return;
    int tc = tcarr[t];
    const float* s = scores + (size_t)t * C;
    float m = -3.0e38f;
    for (int j = 0; j < C; ++j) m = fmaxf(m, s[j]);
    float l = 0.f, stc = 0.f;
    for (int j = 0; j < C; ++j) {
        float v = s[j];
        l += __expf(v - m);
        if (j == tc) stc = v;
    }
    float ce = m + logf(l) - stc;
    bool pos = (tc != 0);
    ce_neg[t] = pos ? 0.f : ce;
    if (pos) atomicAdd(&acc[1], ce);
}

// ---------------- K4: R7 top-k with ONE change: the 20-barrier 1024-entry threshold
// scan is replaced by a wave-shuffle suffix-scan (6 in-wave rounds + 16-entry
// cross-wave suffix; 2 barriers). sfx = wtot[w] + (si - lsum) == old part[tid+1]
// (algebra verified; this exact code path passed correctness inside R10's kernel).
// Histogram, collection, refine, rank, and all float summation order unchanged. ----------------
__global__ void topk_final_kernel(const float* __restrict__ ce_neg,
                                  int* __restrict__ n_pos,
                                  const float* __restrict__ pb_loc,
                                  const float* __restrict__ pb_pce,
                                  const int* __restrict__ pb_npos, int npb,
                                  float* __restrict__ acc, unsigned* __restrict__ done,
                                  int N, int P, unsigned* __restrict__ out) {
    __shared__ unsigned skeys[8732];
    __shared__ int hist[4096];        // aliased as ckeys later
    __shared__ int part[256];
    __shared__ int wtot[16];
    __shared__ int s_tb, s_ca, s_tb2, s_ca2, s_cnt, s_np;
    __shared__ float shf[16];
    int n = blockIdx.x, tid = threadIdx.x;
    int w = tid >> 6, lane = tid & 63;

    int k;
    if (npb > 0) {                    // fused path: reduce per-block partials (wave 0)
        if (tid < 64) {
            float psl = 0.f, psp = 0.f; int psn = 0;
            for (int i = tid; i < npb; i += 64) {
                psl += pb_loc[n * npb + i];
                psp += pb_pce[n * npb + i];
                psn += pb_npos[n * npb + i];
            }
            #pragma unroll
            for (int off = 32; off >= 1; off >>= 1) {
                psl += __shfl_down(psl, off);
                psp += __shfl_down(psp, off);
                psn += __shfl_down(psn, off);
            }
            if (tid == 0) {
                s_np = psn;
                n_pos[n] = psn;                       // plain store; fenced before done++
                if (psl != 0.f) atomicAdd(&acc[0], psl);
                if (psp != 0.f) atomicAdd(&acc[1], psp);
            }
        }
        __syncthreads();
        k = 3 * s_np;
    } else {
        k = 3 * n_pos[n];
    }
    if (k > P) k = P;
    float bsum = 0.f;

    if (k > 0) {                                      // block-uniform
        const float* row = ce_neg + (size_t)n * P;
        for (int i = tid; i < P; i += TK_THREADS) skeys[i] = __float_as_uint(row[i]);
        #pragma unroll
        for (int b = 0; b < 4; ++b) hist[tid * 4 + b] = 0;
        __syncthreads();

        for (int i = tid; i < P; i += TK_THREADS) atomicAdd(&hist[skeys[i] >> 20], 1);
        __syncthreads();

        // ---- threshold bin: shuffle suffix-scan (2 barriers, was 20) ----
        int h0 = hist[tid*4], h1 = hist[tid*4+1], h2 = hist[tid*4+2], h3 = hist[tid*4+3];
        int lsum = h0 + h1 + h2 + h3;
        int si = lsum;
        #pragma unroll
        for (int off = 1; off < 64; off <<= 1) {       // inclusive suffix within wave
            int tv = __shfl_down(si, off);
            if (lane + off < 64) si += tv;
        }
        if (lane == 0) wtot[w] = si;                   // wave totals
        __syncthreads();
        if (tid < 16) {                                // wave 0: exclusive suffix of 16
            int ov = wtot[tid];
            int v = ov;
            #pragma unroll
            for (int off = 1; off < 16; off <<= 1) {
                int tv = __shfl_down(v, off);
                if (lane + off < 16) v += tv;
            }
            wtot[tid] = v - ov;
        }
        __syncthreads();
        int sfx = wtot[w] + (si - lsum);               // == old part[tid+1]
        int sf3 = sfx, sf2 = sfx + h3, sf1 = sf2 + h2, sf0 = sf1 + h1;
        if (sf0 < k && k <= sf0 + h0) { s_tb = tid*4;   s_ca = sf0; }
        if (sf1 < k && k <= sf1 + h1) { s_tb = tid*4+1; s_ca = sf1; }
        if (sf2 < k && k <= sf2 + h2) { s_tb = tid*4+2; s_ca = sf2; }
        if (sf3 < k && k <= sf3 + h3) { s_tb = tid*4+3; s_ca = sf3; }
        __syncthreads();
        int tb = s_tb, kk = k - s_ca;

        if (tid < 256) part[tid] = 0;
        __syncthreads();
        float ssum = 0.f;
        for (int i = tid; i < P; i += TK_THREADS) {
            unsigned key = skeys[i];
            int bin = key >> 20;
            if (bin > tb) ssum += __uint_as_float(key);
            else if (bin == tb) atomicAdd(&part[(key >> 12) & 255u], 1);
        }
        __syncthreads();
        if (tid < 256) {
            int cum = 0;
            for (int b = tid + 1; b < 256; ++b) cum += part[b];
            int h = part[tid];
            if (cum < kk && kk <= cum + h) { s_tb2 = tid; s_ca2 = cum; }
        }
        if (tid == 0) s_cnt = 0;
        __syncthreads();
        int tb2 = s_tb2, kk2 = kk - s_ca2;

        unsigned* ckeys = (unsigned*)hist;
        for (int i = tid; i < P; i += TK_THREADS) {
            unsigned key = skeys[i];
            if ((int)(key >> 20) == tb) {
                int b2 = (key >> 12) & 255u;
                if (b2 > tb2) ssum += __uint_as_float(key);
                else if (b2 == tb2) {
                    int slot = atomicAdd(&s_cnt, 1);
                    if (slot < CK_MAX) ckeys[slot] = key;
                }
            }
        }
        __syncthreads();
        int m = s_cnt; if (m > CK_MAX) m = CK_MAX;
        for (int i = tid; i < m; i += TK_THREADS) {
            unsigned key = ckeys[i];
            int rank = 0;
            for (int j = 0; j < m; ++j) {
                unsigned kj = ckeys[j];
                rank += (kj > key) || (kj == key && j < i);
            }
            if (rank < kk2) ssum += __uint_as_float(key);
        }
        #pragma unroll
        for (int off = 32; off >= 1; off >>= 1) ssum += __shfl_down(ssum, off);
        __syncthreads();
        if ((tid & 63) == 0) shf[tid >> 6] = ssum;
        __syncthreads();
        float tot = 0.f;
        for (int i = 0; i < 16; ++i) tot += shf[i];
        bsum = tot;
    }

    if (tid == 0) {
        if (bsum != 0.f) atomicAdd(&acc[2], bsum);
        __threadfence();                              // release acc adds + n_pos store
        unsigned old = atomicAdd(done, 1u);
        if (old == (unsigned)(N - 1)) {               // last block: finalize
            float a0 = atomicAdd(&acc[0], 0.f);       // atomic reads (acquire-ish)
            float a1 = atomicAdd(&acc[1], 0.f);
            float a2 = atomicAdd(&acc[2], 0.f);
            int tot = 0;
            for (int i = 0; i < N; ++i) tot += n_pos[i];
            float npos = (float)tot;
            float conf = (a2 + a1) / npos;
            float loc  = a0 / (4.f * npos);
            float loss = conf + loc;
            unsigned ub = __float_as_uint(loss);
            unsigned r = (ub + 0x7FFFu + ((ub >> 16) & 1u)) >> 16;  // bf16 RNE
            out[0] = (r << 16) | r;
        }
    }
}

extern "C" void kernel_launch(void* const* d_in, const int* in_sizes, int n_in,
                              void* d_out, int out_size, void* d_ws, size_t ws_size,
                              hipStream_t stream) {
    const float* locs   = (const float*)d_in[0];
    const float* scores = (const float*)d_in[1];
    const float* boxes  = (const float*)d_in[2];
    const int*   labels = (const int*)d_in[3];
    const float* priors = (const float*)d_in[4];

    int P = in_sizes[4] / 4;
    long long NPl = in_sizes[0] / 4;
    int N = (int)(NPl / P);
    int C = (int)((long long)in_sizes[1] / NPl);
    int O = in_sizes[3] / N;
    size_t NP = (size_t)N * P;
    int gx = (P + SBLOCK - 1) / SBLOCK;

    char* ws = (char*)d_ws;
    float*    acc    = (float*)ws;     ws += 16;
    unsigned* done   = (unsigned*)ws;  ws += 16;
    int*      n_pos  = (int*)ws;       ws += (size_t)N * 4;
    int*      pfop   = (int*)ws;       ws += (size_t)N * O * 4;
    float*    pb_loc = (float*)ws;     ws += (size_t)N * gx * 4;
    float*    pb_pce = (float*)ws;     ws += (size_t)N * gx * 4;
    int*      pb_npos= (int*)ws;       ws += (size_t)N * gx * 4;
    int*      tcarr  = (int*)ws;       ws += NP * 4;
    float*    ce_neg = (float*)ws;     ws += NP * 4;

    match_object_kernel<<<N * O, BLOCK, 0, stream>>>(boxes, priors, pfop, acc, n_pos,
                                                     done, N, P, O);
    int npb = 0;
    if (C == 81 && (P % 4) == 0 && O <= MAXO) {
        npb = gx;
        fused_staged_kernel<<<dim3(gx, N), SBLOCK, 0, stream>>>(
            boxes, priors, locs, labels, pfop, scores, ce_neg,
            pb_loc, pb_pce, pb_npos, N, P, O);
    } else {
        int gbx = (P + BLOCK - 1) / BLOCK;
        match_prior_kernel<<<dim3(gbx, N), BLOCK, 0, stream>>>(boxes, priors, locs, labels,
                                                               pfop, tcarr, acc, n_pos, N, P, O);
        loss_generic_kernel<<<(int)((NP + BLOCK - 1) / BLOCK), BLOCK, 0, stream>>>(
            scores, tcarr, ce_neg, acc, (int)NP, C);
    }
    topk_final_kernel<<<N, TK_THREADS, 0, stream>>>(ce_neg, n_pos,
                                                    pb_loc, pb_pce, pb_npos, npb,
                                                    acc, done, N, P, (unsigned*)d_out);
}

// Round 13
// 183.315 us; speedup vs baseline: 1.9875x; 1.0092x over previous
//
#include <hip/hip_runtime.h>
#include <hip/hip_bf16.h>
#include <stdint.h>

#define BLOCK 256
#define TPB 256            // fused threads/block (staging waves x2; grid/LDS unchanged)
#define SROWS 128          // fused rows per block (R7 value)
#define MAXO 64
#define TK_THREADS 1024
#define CK_MAX 4096

// ---------------- K1: per-object argmax over P (block per (n,o)) + init ----------------
__global__ void match_object_kernel(const float* __restrict__ boxes,
                                    const float* __restrict__ priors,
                                    int* __restrict__ pfop,
                                    float* __restrict__ acc, int* __restrict__ n_pos,
                                    unsigned* __restrict__ done, int N, int P, int O) {
    __shared__ unsigned long long swm[4];
    int idx = blockIdx.x, tid = threadIdx.x;
    if (idx == 0) {                       // init for later dispatches (stream-ordered)
        for (int j = tid; j < N; j += BLOCK) n_pos[j] = 0;
        if (tid >= 64 && tid < 67) acc[tid - 64] = 0.f;
        if (tid == 96) *done = 0u;
    }
    const float* b = boxes + (size_t)idx * 4;
    float bx0 = b[0], by0 = b[1], bx1 = b[2], by1 = b[3];
    float areaa = (bx1 - bx0) * (by1 - by0);

    unsigned long long best = 0ULL;
    for (int p = tid; p < P; p += BLOCK) {
        float4 pr = ((const float4*)priors)[p];
        float px0 = pr.x - pr.z * 0.5f, py0 = pr.y - pr.w * 0.5f;
        float px1 = pr.x + pr.z * 0.5f, py1 = pr.y + pr.w * 0.5f;
        float areab = (px1 - px0) * (py1 - py0);
        float ltx = fmaxf(bx0, px0), lty = fmaxf(by0, py0);
        float rbx = fminf(bx1, px1), rby = fminf(by1, py1);
        float wx = fmaxf(rbx - ltx, 0.f), wy = fmaxf(rby - lty, 0.f);
        float inter = wx * wy;
        float iou = inter / (areaa + areab - inter);
        unsigned long long cand = (((unsigned long long)__float_as_uint(iou)) << 32) |
                                  (unsigned long long)(0xFFFFFFFFu - (unsigned)p);
        if (cand > best) best = cand;     // larger iou; tie -> smaller p (numpy first)
    }
    #pragma unroll
    for (int off = 32; off >= 1; off >>= 1) {
        unsigned long long other = __shfl_down(best, off);
        if (other > best) best = other;
    }
    if ((tid & 63) == 0) swm[tid >> 6] = best;
    __syncthreads();
    if (tid == 0) {
        unsigned long long r = swm[0];
        for (int w = 1; w < BLOCK / 64; ++w) if (swm[w] > r) r = swm[w];
        pfop[idx] = (int)(0xFFFFFFFFu - (unsigned)(r & 0xFFFFFFFFull));
    }
}

// ---------------- K2+K3 fused (R7 structure, TPB=256): LDS-bounce, thread-per-row ----------------
// R7 proved this at 47us with 128 threads: 3 blocks/CU x 2 waves = 6 waves/CU, each
// wave issuing 21 serial load->ds_write rounds -> latency-bound (BW floor ~15us).
// Single change: TPB=256 with SROWS=128 -> same grid, same 43.5KB LDS, same 3
// blocks/CU, but 12 waves/CU and ~10 staging rounds per wave (half the chain).
// Consume identical (valid = tid < rows masks threads 128-255). absmax-exact.
__global__ void __launch_bounds__(TPB)
fused_staged_kernel(const float* __restrict__ boxes,
                    const float* __restrict__ priors,
                    const float* __restrict__ locs,
                    const int* __restrict__ labels,
                    const int* __restrict__ pfop,
                    const float* __restrict__ scores,
                    float* __restrict__ ce_neg,
                    float* __restrict__ pb_loc, float* __restrict__ pb_pce,
                    int* __restrict__ pb_npos,
                    int N, int P, int O) {
    __shared__ float4 sstage4[SROWS * 81 / 4];   // 2592 float4 = 41,472 B
    __shared__ float sbx[MAXO * 4];
    __shared__ int   spf[MAXO];
    __shared__ int   slab[MAXO];
    __shared__ float sl[4], sp[4]; __shared__ int sn[4];
    const float* sstage = (const float*)sstage4;

    int n = blockIdx.y, bx = blockIdx.x, tid = threadIdx.x;
    int w = tid >> 6, lane = tid & 63;
    int p0 = bx * SROWS;
    int rows = P - p0; if (rows > SROWS) rows = SROWS;   // rows % 4 == 0 (P % 4 == 0)
    int p = p0 + tid;
    bool valid = tid < rows;                             // threads >= 128 always invalid
    size_t t = (size_t)n * P + p;

    // ---- metadata -> LDS (small), prior/loc -> regs ----
    for (int i = tid; i < O * 4; i += TPB) sbx[i] = boxes[(size_t)n * O * 4 + i];
    for (int i = tid; i < O; i += TPB) { spf[i] = pfop[n * O + i]; slab[i] = labels[n * O + i]; }
    float4 pr = make_float4(0.f, 0.f, 1.f, 1.f);
    float4 pl = make_float4(0.f, 0.f, 0.f, 0.f);
    if (valid) {
        pr = ((const float4*)priors)[p];
        pl = ((const float4*)locs)[t];
    }

    // ---- stage: coalesced float4 copy, identity layout; 256 threads -> 10 rounds ----
    const float4* chunk = (const float4*)(scores + ((size_t)n * P + p0) * 81);
    if (rows == SROWS) {                               // 2592 = 10*256 + 32
        #pragma unroll
        for (int j = 0; j < 10; ++j)                   // idx max 2559 < 2592: unconditional
            sstage4[j * TPB + tid] = chunk[j * TPB + tid];
        if (tid < 32)                                  // tail: 2560..2591
            sstage4[10 * TPB + tid] = chunk[10 * TPB + tid];
    } else {                                           // partial tile (one per image)
        int nf4 = rows * 81 / 4;
        for (int j = 0; j < 11; ++j) {
            int idx = j * TPB + tid;
            if (idx < nf4) sstage4[idx] = chunk[idx];
        }
    }
    __syncthreads();

    // ---- consume: thread-per-row from LDS (rows 0..127 by threads 0..127) ----
    float my_loc = 0.f, my_pce = 0.f; int my_pos = 0;
    if (valid) {
        const float* row = sstage + tid * 81;          // bank stride 17: conflict-free
        float e = 0.f;
        #pragma unroll
        for (int j = 0; j < 81; ++j) e += __expf(row[j]);

        // match (v2 semantics): strict > = first index; forced match last-wins
        float px0 = pr.x - pr.z * 0.5f, py0 = pr.y - pr.w * 0.5f;
        float px1 = pr.x + pr.z * 0.5f, py1 = pr.y + pr.w * 0.5f;
        float areab = (px1 - px0) * (py1 - py0);
        float best = -1.f; int bo = 0;
        for (int o = 0; o < O; ++o) {                  // sbx reads wave-broadcast
            float x0 = sbx[o*4+0], y0 = sbx[o*4+1], x1 = sbx[o*4+2], y1 = sbx[o*4+3];
            float ltx = fmaxf(x0, px0), lty = fmaxf(y0, py0);
            float rbx = fminf(x1, px1), rby = fminf(y1, py1);
            float wx = fmaxf(rbx - ltx, 0.f), wy = fmaxf(rby - lty, 0.f);
            float inter = wx * wy;
            float areao = (x1 - x0) * (y1 - y0);
            float iou = inter / (areao + areab - inter);
            if (iou > best) { best = iou; bo = o; }
        }
        int fo = -1;
        for (int o = 0; o < O; ++o) if (spf[o] == p) fo = o;
        int obj; float ov;
        if (fo >= 0) { obj = fo; ov = 1.0f; }
        else         { obj = bo; ov = best; }
        int tc = (ov < 0.5f) ? 0 : slab[obj];

        float stc = row[tc];                           // free: already staged
        float ce = logf(e) - stc;
        bool pos = (tc != 0);
        ce_neg[t] = pos ? 0.f : ce;                    // coalesced store
        if (pos) {
            my_pce = ce; my_pos = 1;
            float x0 = sbx[obj*4+0], y0 = sbx[obj*4+1], x1 = sbx[obj*4+2], y1 = sbx[obj*4+3];
            float cx = (x0 + x1) * 0.5f, cy = (y0 + y1) * 0.5f;
            float bw = x1 - x0, bh = y1 - y0;
            float g0 = (cx - pr.x) / (pr.z / 10.0f);
            float g1 = (cy - pr.y) / (pr.w / 10.0f);
            float g2 = logf(bw / pr.z) * 5.0f;
            float g3 = logf(bh / pr.w) * 5.0f;
            my_loc = fabsf(pl.x-g0) + fabsf(pl.y-g1) + fabsf(pl.z-g2) + fabsf(pl.w-g3);
        }
    }

    // ---- block partials: plain stores, no atomics (4 waves; 2 upper are zeros) ----
    #pragma unroll
    for (int off = 32; off >= 1; off >>= 1) {
        my_loc += __shfl_down(my_loc, off);
        my_pce += __shfl_down(my_pce, off);
        my_pos += __shfl_down(my_pos, off);
    }
    if (lane == 0) { sl[w] = my_loc; sp[w] = my_pce; sn[w] = my_pos; }
    __syncthreads();
    if (tid == 0) {
        int npb = gridDim.x;
        pb_loc[n * npb + bx]  = (sl[0] + sl[1]) + (sl[2] + sl[3]);
        pb_pce[n * npb + bx]  = (sp[0] + sp[1]) + (sp[2] + sp[3]);
        pb_npos[n * npb + bx] = sn[0] + sn[1] + sn[2] + sn[3];
    }
}

// ---------------- fallback K2: per-prior match -> tcarr (any C path) ----------------
__global__ void match_prior_kernel(const float* __restrict__ boxes,
                                   const float* __restrict__ priors,
                                   const float* __restrict__ locs,
                                   const int* __restrict__ labels,
                                   const int* __restrict__ pfop,
                                   int* __restrict__ tcarr,
                                   float* __restrict__ acc, int* __restrict__ n_pos,
                                   int N, int P, int O) {
    __shared__ float sbx[MAXO * 4];
    __shared__ float sarea[MAXO];
    __shared__ int   spf[MAXO];
    __shared__ int   slab[MAXO];
    int n = blockIdx.y, tid = threadIdx.x;
    if (tid < O * 4) sbx[tid] = boxes[(size_t)n * O * 4 + tid];
    if (tid >= 128 && tid < 128 + O) spf[tid - 128]  = pfop[n * O + (tid - 128)];
    if (tid >= 192 && tid < 192 + O) slab[tid - 192] = labels[n * O + (tid - 192)];
    __syncthreads();
    if (tid < O)
        sarea[tid] = (sbx[tid*4+2] - sbx[tid*4+0]) * (sbx[tid*4+3] - sbx[tid*4+1]);
    __syncthreads();

    int p = blockIdx.x * BLOCK + tid;
    bool valid = p < P;
    float my_loc = 0.f; int my_pos = 0;
    if (valid) {
        float4 pr = ((const float4*)priors)[p];
        float px0 = pr.x - pr.z * 0.5f, py0 = pr.y - pr.w * 0.5f;
        float px1 = pr.x + pr.z * 0.5f, py1 = pr.y + pr.w * 0.5f;
        float areab = (px1 - px0) * (py1 - py0);

        float best = -1.f; int bo = 0;
        for (int o = 0; o < O; ++o) {
            float ltx = fmaxf(sbx[o*4+0], px0);
            float lty = fmaxf(sbx[o*4+1], py0);
            float rbx = fminf(sbx[o*4+2], px1);
            float rby = fminf(sbx[o*4+3], py1);
            float wx = fmaxf(rbx - ltx, 0.f), wy = fmaxf(rby - lty, 0.f);
            float inter = wx * wy;
            float iou = inter / (sarea[o] + areab - inter);
            if (iou > best) { best = iou; bo = o; }
        }
        int fo = -1;
        for (int o = 0; o < O; ++o) if (spf[o] == p) fo = o;
        int obj; float ov;
        if (fo >= 0) { obj = fo; ov = 1.0f; }
        else         { obj = bo; ov = best; }
        int lab = slab[obj];
        int tc = (ov < 0.5f) ? 0 : lab;
        tcarr[(size_t)n * P + p] = tc;
        if (tc != 0) {
            my_pos = 1;
            float x0 = sbx[obj*4+0], y0 = sbx[obj*4+1], x1 = sbx[obj*4+2], y1 = sbx[obj*4+3];
            float cx = (x0 + x1) * 0.5f, cy = (y0 + y1) * 0.5f;
            float w = x1 - x0, h = y1 - y0;
            float g0 = (cx - pr.x) / (pr.z / 10.0f);
            float g1 = (cy - pr.y) / (pr.w / 10.0f);
            float g2 = logf(w / pr.z) * 5.0f;
            float g3 = logf(h / pr.w) * 5.0f;
            const float* pl = locs + ((size_t)n * P + p) * 4;
            my_loc = fabsf(pl[0]-g0) + fabsf(pl[1]-g1) + fabsf(pl[2]-g2) + fabsf(pl[3]-g3);
        }
    }
    #pragma unroll
    for (int off = 32; off >= 1; off >>= 1) {
        my_loc += __shfl_down(my_loc, off);
        my_pos += __shfl_down(my_pos, off);
    }
    if ((tid & 63) == 0 && my_pos) {
        atomicAdd(&acc[0], my_loc);
        atomicAdd(&n_pos[n], my_pos);
    }
}

// ---------------- generic fallback (any C) ----------------
__global__ void loss_generic_kernel(const float* __restrict__ scores,
                                    const int* __restrict__ tcarr,
                                    float* __restrict__ ce_neg, float* __restrict__ acc,
                                    int NP, int C) {
    int t = blockIdx.x * blockDim.x + threadIdx.x;
    if (t >= NP) return;
    int tc = tcarr[t];
    const float* s = scores + (size_t)t * C;
    float m = -3.0e38f;
    for (int j = 0; j < C; ++j) m = fmaxf(m, s[j]);
    float l = 0.f, stc = 0.f;
    for (int j = 0; j < C; ++j) {
        float v = s[j];
        l += __expf(v - m);
        if (j == tc) stc = v;
    }
    float ce = m + logf(l) - stc;
    bool pos = (tc != 0);
    ce_neg[t] = pos ? 0.f : ce;
    if (pos) atomicAdd(&acc[1], ce);
}

// ---------------- K4: R7-exact top-k sum per row + partial-reduce + final combine ----------------
__global__ void topk_final_kernel(const float* __restrict__ ce_neg,
                                  int* __restrict__ n_pos,
                                  const float* __restrict__ pb_loc,
                                  const float* __restrict__ pb_pce,
                                  const int* __restrict__ pb_npos, int npb,
                                  float* __restrict__ acc, unsigned* __restrict__ done,
                                  int N, int P, unsigned* __restrict__ out) {
    __shared__ unsigned skeys[8732];
    __shared__ int hist[4096];        // aliased as ckeys later
    __shared__ int part[1024];
    __shared__ int s_tb, s_ca, s_tb2, s_ca2, s_cnt, s_np;
    __shared__ float shf[16];
    int n = blockIdx.x, tid = threadIdx.x;

    int k;
    if (npb > 0) {                    // fused path: reduce per-block partials (wave 0)
        if (tid < 64) {
            float psl = 0.f, psp = 0.f; int psn = 0;
            for (int i = tid; i < npb; i += 64) {
                psl += pb_loc[n * npb + i];
                psp += pb_pce[n * npb + i];
                psn += pb_npos[n * npb + i];
            }
            #pragma unroll
            for (int off = 32; off >= 1; off >>= 1) {
                psl += __shfl_down(psl, off);
                psp += __shfl_down(psp, off);
                psn += __shfl_down(psn, off);
            }
            if (tid == 0) {
                s_np = psn;
                n_pos[n] = psn;                       // plain store; fenced before done++
                if (psl != 0.f) atomicAdd(&acc[0], psl);
                if (psp != 0.f) atomicAdd(&acc[1], psp);
            }
        }
        __syncthreads();
        k = 3 * s_np;
    } else {
        k = 3 * n_pos[n];
    }
    if (k > P) k = P;
    float bsum = 0.f;

    if (k > 0) {                                      // block-uniform
        const float* row = ce_neg + (size_t)n * P;
        for (int i = tid; i < P; i += TK_THREADS) skeys[i] = __float_as_uint(row[i]);
        #pragma unroll
        for (int b = 0; b < 4; ++b) hist[tid * 4 + b] = 0;
        __syncthreads();

        for (int i = tid; i < P; i += TK_THREADS) atomicAdd(&hist[skeys[i] >> 20], 1);
        __syncthreads();
        int h0 = hist[tid*4], h1 = hist[tid*4+1], h2 = hist[tid*4+2], h3 = hist[tid*4+3];
        part[tid] = h0 + h1 + h2 + h3;
        __syncthreads();
        for (int s = 1; s < 1024; s <<= 1) {
            int v = part[tid] + ((tid + s < 1024) ? part[tid + s] : 0);
            __syncthreads();
            part[tid] = v;
            __syncthreads();
        }
        int sfx = (tid + 1 < 1024) ? part[tid + 1] : 0;
        int sf3 = sfx, sf2 = sfx + h3, sf1 = sf2 + h2, sf0 = sf1 + h1;
        if (sf0 < k && k <= sf0 + h0) { s_tb = tid*4;   s_ca = sf0; }
        if (sf1 < k && k <= sf1 + h1) { s_tb = tid*4+1; s_ca = sf1; }
        if (sf2 < k && k <= sf2 + h2) { s_tb = tid*4+2; s_ca = sf2; }
        if (sf3 < k && k <= sf3 + h3) { s_tb = tid*4+3; s_ca = sf3; }
        __syncthreads();
        int tb = s_tb, kk = k - s_ca;

        if (tid < 256) part[tid] = 0;
        __syncthreads();
        float ssum = 0.f;
        for (int i = tid; i < P; i += TK_THREADS) {
            unsigned key = skeys[i];
            int bin = key >> 20;
            if (bin > tb) ssum += __uint_as_float(key);
            else if (bin == tb) atomicAdd(&part[(key >> 12) & 255u], 1);
        }
        __syncthreads();
        if (tid < 256) {
            int cum = 0;
            for (int b = tid + 1; b < 256; ++b) cum += part[b];
            int h = part[tid];
            if (cum < kk && kk <= cum + h) { s_tb2 = tid; s_ca2 = cum; }
        }
        if (tid == 0) s_cnt = 0;
        __syncthreads();
        int tb2 = s_tb2, kk2 = kk - s_ca2;

        unsigned* ckeys = (unsigned*)hist;
        for (int i = tid; i < P; i += TK_THREADS) {
            unsigned key = skeys[i];
            if ((int)(key >> 20) == tb) {
                int b2 = (key >> 12) & 255u;
                if (b2 > tb2) ssum += __uint_as_float(key);
                else if (b2 == tb2) {
                    int slot = atomicAdd(&s_cnt, 1);
                    if (slot < CK_MAX) ckeys[slot] = key;
                }
            }
        }
        __syncthreads();
        int m = s_cnt; if (m > CK_MAX) m = CK_MAX;
        for (int i = tid; i < m; i += TK_THREADS) {
            unsigned key = ckeys[i];
            int rank = 0;
            for (int j = 0; j < m; ++j) {
                unsigned kj = ckeys[j];
                rank += (kj > key) || (kj == key && j < i);
            }
            if (rank < kk2) ssum += __uint_as_float(key);
        }
        #pragma unroll
        for (int off = 32; off >= 1; off >>= 1) ssum += __shfl_down(ssum, off);
        __syncthreads();
        if ((tid & 63) == 0) shf[tid >> 6] = ssum;
        __syncthreads();
        float tot = 0.f;
        for (int i = 0; i < 16; ++i) tot += shf[i];
        bsum = tot;
    }

    if (tid == 0) {
        if (bsum != 0.f) atomicAdd(&acc[2], bsum);
        __threadfence();                              // release acc adds + n_pos store
        unsigned old = atomicAdd(done, 1u);
        if (old == (unsigned)(N - 1)) {               // last block: finalize
            float a0 = atomicAdd(&acc[0], 0.f);       // atomic reads (acquire-ish)
            float a1 = atomicAdd(&acc[1], 0.f);
            float a2 = atomicAdd(&acc[2], 0.f);
            int tot = 0;
            for (int i = 0; i < N; ++i) tot += n_pos[i];
            float npos = (float)tot;
            float conf = (a2 + a1) / npos;
            float loc  = a0 / (4.f * npos);
            float loss = conf + loc;
            unsigned ub = __float_as_uint(loss);
            unsigned r = (ub + 0x7FFFu + ((ub >> 16) & 1u)) >> 16;  // bf16 RNE
            out[0] = (r << 16) | r;
        }
    }
}

extern "C" void kernel_launch(void* const* d_in, const int* in_sizes, int n_in,
                              void* d_out, int out_size, void* d_ws, size_t ws_size,
                              hipStream_t stream) {
    const float* locs   = (const float*)d_in[0];
    const float* scores = (const float*)d_in[1];
    const float* boxes  = (const float*)d_in[2];
    const int*   labels = (const int*)d_in[3];
    const float* priors = (const float*)d_in[4];

    int P = in_sizes[4] / 4;
    long long NPl = in_sizes[0] / 4;
    int N = (int)(NPl / P);
    int C = (int)((long long)in_sizes[1] / NPl);
    int O = in_sizes[3] / N;
    size_t NP = (size_t)N * P;
    int gx = (P + SROWS - 1) / SROWS;

    char* ws = (char*)d_ws;
    float*    acc    = (float*)ws;     ws += 16;
    unsigned* done   = (unsigned*)ws;  ws += 16;
    int*      n_pos  = (int*)ws;       ws += (size_t)N * 4;
    int*      pfop   = (int*)ws;       ws += (size_t)N * O * 4;
    float*    pb_loc = (float*)ws;     ws += (size_t)N * gx * 4;
    float*    pb_pce = (float*)ws;     ws += (size_t)N * gx * 4;
    int*      pb_npos= (int*)ws;       ws += (size_t)N * gx * 4;
    int*      tcarr  = (int*)ws;       ws += NP * 4;
    float*    ce_neg = (float*)ws;     ws += NP * 4;

    match_object_kernel<<<N * O, BLOCK, 0, stream>>>(boxes, priors, pfop, acc, n_pos,
                                                     done, N, P, O);
    int npb = 0;
    if (C == 81 && (P % 4) == 0 && O <= MAXO) {
        npb = gx;
        fused_staged_kernel<<<dim3(gx, N), TPB, 0, stream>>>(
            boxes, priors, locs, labels, pfop, scores, ce_neg,
            pb_loc, pb_pce, pb_npos, N, P, O);
    } else {
        int gbx = (P + BLOCK - 1) / BLOCK;
        match_prior_kernel<<<dim3(gbx, N), BLOCK, 0, stream>>>(boxes, priors, locs, labels,
                                                               pfop, tcarr, acc, n_pos, N, P, O);
        loss_generic_kernel<<<(int)((NP + BLOCK - 1) / BLOCK), BLOCK, 0, stream>>>(
            scores, tcarr, ce_neg, acc, (int)NP, C);
    }
    topk_final_kernel<<<N, TK_THREADS, 0, stream>>>(ce_neg, n_pos,
                                                    pb_loc, pb_pce, pb_npos, npb,
                                                    acc, done, N, P, (unsigned*)d_out);
}